// Round 16
// baseline (236.575 us; speedup 1.0000x reference)
//
#include <hip/hip_runtime.h>
#include <math.h>

typedef unsigned short u16;
typedef short bf8 __attribute__((ext_vector_type(8)));      // 8 bf16 (raw bits)
typedef float f32x4 __attribute__((ext_vector_type(4)));

__device__ __forceinline__ u16 f2b(float f) {
    union { float f; unsigned u; } x; x.f = f;
    return (u16)((x.u + 0x7FFFu + ((x.u >> 16) & 1u)) >> 16);   // RTNE
}
__device__ __forceinline__ float b2f(u16 b) {
    union { unsigned u; float f; } x; x.u = ((unsigned)b) << 16;
    return x.f;
}

__device__ __forceinline__ void async16(const void* g, void* l) {
    __builtin_amdgcn_global_load_lds(
        (const __attribute__((address_space(1))) unsigned int*)g,
        (__attribute__((address_space(3))) unsigned int*)l, 16, 0, 0);
}

__device__ __forceinline__ void cstore(float* p, float v) { *p = v; }
__device__ __forceinline__ void cstore(u16* p, float v) { *p = f2b(v); }

// ---------------- bf16 MFMA GEMM (m97 structure): C[M,N] = A[M,K] @ Bt[N,K]^T ------
// BK=32 (R12: BK=64 regressed — barrier drain scales with bytes, not count).
// R14 K-FUSION (neutral but harmless, kept): K-blocks (col0 in [1024,2048))
// write scaled fragments straight to Kp; f2b(acc*0.125) bit-identical to the
// old round->scale->round chain (power-of-2 scale).
// R15 V-FUSION (WIN, -6us): V-blocks (col0 >= 2048) transpose acc through a
// 32KB LDS tile (reusing As/Bs — dead after the K-loop's trailing barrier)
// and emit Vp fragments directly; pack_v kernel deleted. Fragment map
// verified vs pack_v; bit-identical. qkvb V region dead (only Q cols live).
template<typename OutT>
__global__ __launch_bounds__(256) void gemm_mfma(const u16* __restrict__ A,
                                                 const u16* __restrict__ Bt,
                                                 OutT* __restrict__ C,
                                                 u16* __restrict__ KP,
                                                 u16* __restrict__ VP,
                                                 int M, int N, int K) {
    __shared__ __align__(16) u16 sh[128 * 128];    // K-loop: As=[0,4096) Bs=[4096,8192); epilogue: ts[128][128]
    u16* As = sh;
    u16* Bs = sh + 128 * 32;
    const int tid = threadIdx.x;
    const int w = tid >> 6, L = tid & 63;
    const int l15 = L & 15, quad = L >> 4;
    const int wm = (w >> 1) * 64, wn = (w & 1) * 64;
    const int row0 = blockIdx.y * 128, col0 = blockIdx.x * 128;
    const int laneRow = L >> 2, laneCol8 = (L & 3) * 8;

    f32x4 acc[4][4] = {};

    for (int k0 = 0; k0 < K; k0 += 32) {
        #pragma unroll
        for (int i = 0; i < 2; ++i) {
            const int seg = w * 2 + i;
            const int r = seg * 16 + laneRow;
            async16(&A[(size_t)(row0 + r) * K + k0 + laneCol8], &As[seg * 512 + L * 8]);
        }
        #pragma unroll
        for (int i = 0; i < 2; ++i) {
            const int seg = w * 2 + i;
            const int r = seg * 16 + laneRow;
            async16(&Bt[(size_t)(col0 + r) * K + k0 + laneCol8], &Bs[seg * 512 + L * 8]);
        }
        __syncthreads();
        bf8 a[4], b[4];
        #pragma unroll
        for (int mt = 0; mt < 4; ++mt)
            a[mt] = *(const bf8*)&As[(wm + mt * 16 + l15) * 32 + quad * 8];
        #pragma unroll
        for (int nt = 0; nt < 4; ++nt)
            b[nt] = *(const bf8*)&Bs[(wn + nt * 16 + l15) * 32 + quad * 8];
        #pragma unroll
        for (int mt = 0; mt < 4; ++mt)
            #pragma unroll
            for (int nt = 0; nt < 4; ++nt)
                acc[mt][nt] = __builtin_amdgcn_mfma_f32_16x16x32_bf16(
                    a[mt], b[nt], acc[mt][nt], 0, 0, 0);
        __syncthreads();
    }
    if (VP != nullptr && col0 >= 2048) {
        // V-block: transpose through LDS, emit Vp fragments (pack_v fused here)
        u16* ts = sh;                              // [s_local][hl*64 + d], 128x128
        #pragma unroll
        for (int mt = 0; mt < 4; ++mt)
            #pragma unroll
            for (int nt = 0; nt < 4; ++nt) {
                const int cloc = wn + nt * 16 + l15;
                #pragma unroll
                for (int r = 0; r < 4; ++r) {
                    const int rloc = wm + mt * 16 + quad * 4 + r;
                    ts[rloc * 128 + cloc] = f2b(acc[mt][nt][r]);
                }
            }
        __syncthreads();
        const int b = row0 >> 10;
        const int h0 = (col0 - 2048) >> 6;
        const int c32base = (row0 >> 5) & 31;
        #pragma unroll
        for (int j = 0; j < 8; ++j) {
            const int f = j * 256 + tid;           // frag id in [0, 2048)
            const int hl = f >> 10, tn2 = (f >> 8) & 3, c32l = (f >> 6) & 3;
            const int Lf = f & 63, l15f = f & 15, quadf = (f >> 4) & 3;
            __align__(16) u16 buf[8];
            #pragma unroll
            for (int i = 0; i < 8; ++i)
                buf[i] = ts[(c32l * 32 + quadf * 8 + i) * 128 + hl * 64 + tn2 * 16 + l15f];
            const int bh = (b << 4) + h0 + hl;
            *(uint4*)(VP + ((size_t)(bh * 8192 + tn2 * 2048 + (c32base + c32l) * 64 + Lf) << 3))
                = *(uint4*)buf;
        }
    } else if (KP != nullptr && col0 >= 1024) {
        // K-block: emit fragment-linear Kp (pre-scaled by 1/8)
        #pragma unroll
        for (int mt = 0; mt < 4; ++mt)
            #pragma unroll
            for (int nt = 0; nt < 4; ++nt) {
                const int hd = col0 - 1024 + wn + nt * 16 + l15;
                const int h = hd >> 6, d = hd & 63;
                const int doff = ((d >> 5) << 6) + (((d >> 3) & 3) << 4);
                #pragma unroll
                for (int r = 0; r < 4; ++r) {
                    const int row = row0 + wm + mt * 16 + quad * 4 + r;
                    const int b = row >> 10, s = row & 1023;
                    const size_t idx =
                        ((size_t)((((b << 4) + h) << 13) + ((s >> 4) << 7) + doff + (s & 15)) << 3)
                        + (d & 7);
                    KP[idx] = f2b(acc[mt][nt][r] * 0.125f);
                }
            }
    } else {
        #pragma unroll
        for (int mt = 0; mt < 4; ++mt)
            #pragma unroll
            for (int nt = 0; nt < 4; ++nt) {
                const int col = col0 + wn + nt * 16 + l15;
                #pragma unroll
                for (int r = 0; r < 4; ++r) {
                    const int row = row0 + wm + mt * 16 + quad * 4 + r;
                    cstore(&C[(size_t)row * N + col], acc[mt][nt][r]);
                }
            }
    }
}

// ---------------- 64x64-tile variant (gemm2): 4 blocks/CU -------------------------
// R16: gemm2 block-count ladder continues (R7 evidence: 128x128 @1 blk/CU ->
// 64x128 @2 blk/CU was a clear win; block count is gemm2's binding constraint).
// 64(M)x64(N) tile -> grid (16,64) = 1024 blocks = 4 blocks/CU. Symmetric
// staging (A and B each 256 chunks, 1/thread), LDS 8KB, wave owns 32x32:
// acc[2][2], 4 MFMA/K-step. Extra A/B re-reads are L2-resident (wpT 2MB,
// ymidb 8MB). BK=32 (R12: BK=64 regressed).
template<typename OutT>
__global__ __launch_bounds__(256) void gemm_mfma64x64(const u16* __restrict__ A,
                                                      const u16* __restrict__ Bt,
                                                      OutT* __restrict__ C,
                                                      int M, int N, int K) {
    __shared__ __align__(16) u16 As[64 * 32];
    __shared__ __align__(16) u16 Bs[64 * 32];
    const int tid = threadIdx.x;
    const int w = tid >> 6, L = tid & 63;
    const int l15 = L & 15, quad = L >> 4;
    const int wm = (w >> 1) * 32, wn = (w & 1) * 32;
    const int row0 = blockIdx.y * 64, col0 = blockIdx.x * 64;
    const int laneRow = L >> 2, laneCol8 = (L & 3) * 8;   // 4 threads/row, 64B runs

    f32x4 acc[2][2] = {};

    for (int k0 = 0; k0 < K; k0 += 32) {
        {   // A: 64x32 = 256 chunks, one per thread
            const int r = w * 16 + laneRow;
            async16(&A[(size_t)(row0 + r) * K + k0 + laneCol8], &As[w * 512 + L * 8]);
        }
        {   // B: 64x32 = 256 chunks, one per thread
            const int r = w * 16 + laneRow;
            async16(&Bt[(size_t)(col0 + r) * K + k0 + laneCol8], &Bs[w * 512 + L * 8]);
        }
        __syncthreads();
        bf8 a[2], b[2];
        #pragma unroll
        for (int mt = 0; mt < 2; ++mt)
            a[mt] = *(const bf8*)&As[(wm + mt * 16 + l15) * 32 + quad * 8];
        #pragma unroll
        for (int nt = 0; nt < 2; ++nt)
            b[nt] = *(const bf8*)&Bs[(wn + nt * 16 + l15) * 32 + quad * 8];
        #pragma unroll
        for (int mt = 0; mt < 2; ++mt)
            #pragma unroll
            for (int nt = 0; nt < 2; ++nt)
                acc[mt][nt] = __builtin_amdgcn_mfma_f32_16x16x32_bf16(
                    a[mt], b[nt], acc[mt][nt], 0, 0, 0);
        __syncthreads();
    }
    #pragma unroll
    for (int mt = 0; mt < 2; ++mt)
        #pragma unroll
        for (int nt = 0; nt < 2; ++nt) {
            const int col = col0 + wn + nt * 16 + l15;
            #pragma unroll
            for (int r = 0; r < 4; ++r) {
                const int row = row0 + wm + mt * 16 + quad * 4 + r;
                cstore(&C[(size_t)row * N + col], acc[mt][nt][r]);
            }
        }
}

// ---------------- merged prep: x->bf16, EKP/EVP fragment tables, weight transposes --
__global__ __launch_bounds__(256) void prep_all(const float* __restrict__ x,
                                                const float* __restrict__ embk,
                                                const float* __restrict__ embv,
                                                const float* __restrict__ w_attn,
                                                const float* __restrict__ w_proj,
                                                u16* __restrict__ xb,
                                                u16* __restrict__ EKP,
                                                u16* __restrict__ EVP,
                                                u16* __restrict__ waT,
                                                u16* __restrict__ wpT) {
    __shared__ u16 ts[64][65];
    const int bx = blockIdx.x;
    const int tid = threadIdx.x;
    if (bx < 4096) {
        int idx = bx * 256 + tid;
        const float4 v = ((const float4*)x)[idx];
        ((ushort4*)xb)[idx] = make_ushort4(f2b(v.x), f2b(v.y), f2b(v.z), f2b(v.w));
    } else if (bx < 4132) {
        int t = (bx - 4096) * 256 + tid;           // [0, 9216)
        int L = t & 63, kc = (t >> 6) & 1, k16 = t >> 7;
        int l15 = L & 15, quad = L >> 4;
        int row = 1 + k16 * 16 + l15;
        int d = row - 128;
        int cl = d < 0 ? 0 : (d > 1023 ? 1023 : d);
        const float* p = embk + cl * 64 + kc * 32 + quad * 8;
        #pragma unroll
        for (int i = 0; i < 8; ++i) EKP[t * 8 + i] = f2b(p[i]);
    } else if (bx < 4168) {
        int t = (bx - 4132) * 256 + tid;           // [0, 9216)
        int L = t & 63, rest = t >> 6;             // rest = tn*36 + c32
        int c32 = rest % 36, tn = rest / 36;
        int l15 = L & 15, quad = L >> 4;
        #pragma unroll
        for (int i = 0; i < 8; ++i) {
            int c = c32 * 32 + quad * 8 + i;
            int d = c - 127;
            int cl = d < 0 ? 0 : (d > 1023 ? 1023 : d);
            EVP[t * 8 + i] = f2b(embv[cl * 64 + tn * 16 + l15]);
        }
    } else {
        const float* W; u16* WT; int Cc, t;
        if (bx < 4168 + 768) { t = bx - 4168; W = w_attn; WT = waT; Cc = 3072; }
        else                 { t = bx - 4936; W = w_proj; WT = wpT; Cc = 1024; }
        const int nx = Cc >> 6;
        const int c0 = (t % nx) * 64, r0 = (t / nx) * 64;
        for (int i = tid; i < 4096; i += 256) {
            int r = i >> 6, c = i & 63;
            ts[r][c] = f2b(W[(size_t)(r0 + r) * Cc + c0 + c]);
        }
        __syncthreads();
        for (int i = tid; i < 4096; i += 256) {
            int c = i >> 6, r = i & 63;
            WT[(size_t)(c0 + c) * 1024 + r0 + r] = ts[r][c];
        }
    }
}

// cumulative chunk counts: tile t owns units [S(t), S(t)+t/2+1); S(16)=72 total.
__device__ const int d_S[17] = {0,1,2,4,6,9,12,16,20,25,30,36,42,49,56,64,72};
// partial-slot base per split tile (tiles 4, 8..15), compact: 19 slots per bh.
// tile:       0  1  2  3  4  5  6  7  8  9 10 11 12 13 14 15
__device__ const int d_SB[16] = {0,0,0,0, 0,0,0,0, 2, 4, 6, 8,10,13,15,17};

// ---------------- MFMA fused attention with RPE: split-barrier staged pipeline -----
// grid (18, 64), unit-split (R6). R8 schedule — PROVEN 81-97us (session band):
//   bar1 = __syncthreads (drain ~free) -> issue K DMA -> S2 EKP stream covers
//   K latency -> [sched_barrier] -> issue V DMA LAST -> asm vmcnt(4) waits
//   ONLY the 4 older K-DMAs/thread (V stays in flight) -> raw s_barrier ->
//   S1 consumes K while V's latency hides under softmax+scatter -> bar3 =
//   __syncthreads (drain ~free, V landed) -> PV + P'EV. s_setprio(1) wraps
//   MFMA clusters (attn +4-7%, m191).
// R9/R10 LESSON: deeper cross-unit pipelining inflated VGPR 124->148, dropped
// occupancy 16.5->10.2%, DOUBLED attn time. Occupancy >= scheduling here —
// keep this body register-lean. Plain __launch_bounds__(256): min-waves hints
// force spills (R3/R4). Direct-global K/V loses 25-60% (R1/R5) — keep staging.
__global__ __launch_bounds__(256) void attn_mfma(const u16* __restrict__ qkvb,
                                                 const u16* __restrict__ Kp,
                                                 const u16* __restrict__ Vp,
                                                 const u16* __restrict__ EKP,
                                                 const u16* __restrict__ EVP,
                                                 u16* __restrict__ yb,
                                                 float* __restrict__ po,
                                                 float* __restrict__ lsp) {
    __shared__ __align__(16) u16 slab_[4][2560];   // 20480 B, per-wave overlay
    __shared__ __align__(16) u16 KVs[16384];       // 32768 B: K [0..8192), V [8192..)

    const int tid = threadIdx.x;
    const int w = tid >> 6, L = tid & 63;
    const int l15 = L & 15, quad = L >> 4;
    const int blk = blockIdx.x;
    const int bh = blockIdx.y, b = bh >> 4, h = bh & 15;
    u16* S2l = slab_[w];
    u16* Pl  = slab_[w];
    u16* Ppl = slab_[w];

    const bf8* EKPF = (const bf8*)EKP;
    const bf8* EVPF = (const bf8*)EVP;

    bf8 qn[2];
    f32x4 o[4];
    float lsum[4];
    int t = -1, t0 = 0;

    auto flush = [&](int tt) {
        float lr[4];
        #pragma unroll
        for (int r = 0; r < 4; ++r) {
            float s = lsum[r];
            s += __shfl_xor(s, 1); s += __shfl_xor(s, 2);
            s += __shfl_xor(s, 4); s += __shfl_xor(s, 8);
            lr[r] = s;
        }
        const bool whole = (d_S[tt] >> 2) == ((d_S[tt + 1] - 1) >> 2);
        if (whole) {           // all units of this tile in this block: finalize
            #pragma unroll
            for (int tn = 0; tn < 4; ++tn) {
                const int col = h * 64 + tn * 16 + l15;
                #pragma unroll
                for (int r = 0; r < 4; ++r) {
                    const int trow = tt * 64 + w * 16 + quad * 4 + r;
                    yb[(size_t)(b * 1024 + trow) * 1024 + col] = f2b(o[tn][r] / lr[r]);
                }
            }
        } else {               // partial: statically-indexed slot
            const int slot = blk - (d_S[tt] >> 2);
            const size_t sidx = (size_t)(bh * 19 + d_SB[tt] + slot);
            float* pob = po + (sidx << 12);
            #pragma unroll
            for (int tn = 0; tn < 4; ++tn)
                #pragma unroll
                for (int r = 0; r < 4; ++r)
                    pob[(w * 16 + quad * 4 + r) * 64 + tn * 16 + l15] = o[tn][r];
            if (l15 == 0) {
                float* lsb = lsp + (sidx << 6);
                #pragma unroll
                for (int r = 0; r < 4; ++r) lsb[w * 16 + quad * 4 + r] = lr[r];
            }
        }
    };

    #pragma unroll 1
    for (int ui = 0; ui < 4; ++ui) {
        const int u = blk * 4 + ui;
        int nt = (t < 0) ? 0 : t;
        while (d_S[nt + 1] <= u) ++nt;
        if (nt != t) {
            if (t >= 0) flush(t);
            t = nt; t0 = t * 64;
            const int trow = t0 + w * 16 + l15;
            const u16* qp = qkvb + (size_t)(b * 1024 + trow) * 3072 + h * 64 + quad * 8;
            qn[0] = *(const bf8*)qp;
            qn[1] = *(const bf8*)(qp + 32);
            #pragma unroll
            for (int tn = 0; tn < 4; ++tn)
                #pragma unroll
                for (int j = 0; j < 4; ++j) o[tn][j] = 0.f;
            #pragma unroll
            for (int r = 0; r < 4; ++r) lsum[r] = 0.f;
        }
        const int c = u - d_S[t];
        const int s0 = c << 7;
        const int diff = t0 - s0;                 // >= 0, multiple of 64

        __syncthreads();    // bar1: prior unit's LDS reads retired (drain ~free)

        // ---- issue K DMA only (16 KB contiguous) ----
        {
            const size_t kbase = ((size_t)(bh * 64 + (s0 >> 4)) << 1) * 512;
            #pragma unroll
            for (int i = 0; i < 4; ++i)
                async16(Kp + kbase + (i * 256 + tid) * 8, &KVs[(i * 256 + tid) * 8]);
        }

        // ---- S2 = Q @ EK^T (global EKP stream; covers K DMA latency) ----
        f32x4 s2[9] = {};
        {
            const int kb = (diff >> 4) + w;       // k16 base
            #pragma unroll
            for (int j = 0; j < 9; ++j) {
                #pragma unroll
                for (int kc = 0; kc < 2; ++kc)
                    s2[j] = __builtin_amdgcn_mfma_f32_16x16x32_bf16(
                        qn[kc], EKPF[(((kb + j) << 1) + kc) * 64 + L], s2[j], 0, 0, 0);
            }
        }
        #pragma unroll
        for (int j = 0; j < 9; ++j)
            #pragma unroll
            for (int r = 0; r < 4; ++r)
                S2l[(quad * 4 + r) * 148 + j * 16 + l15] = f2b(s2[j][r]);

        // ---- issue V DMA LAST (latency hides under S1 + softmax + scatter) ----
        __builtin_amdgcn_sched_barrier(0);   // pin V issue after all S2 loads
        {
            const int vb = bh * 128 + (s0 >> 5);
            #pragma unroll
            for (int i = 0; i < 4; ++i)
                async16(Vp + ((size_t)(vb + i * 32) * 512 + tid * 8),
                        &KVs[8192 + i * 2048 + tid * 8]);
        }

        // ---- wait K only (4 oldest VMEM; V stays in flight), rendezvous ----
        asm volatile("s_waitcnt vmcnt(4)" ::: "memory");
        __builtin_amdgcn_s_barrier();
        __builtin_amdgcn_sched_barrier(0);

        // ---- S1 = Q @ (K/8)^T from LDS ----
        f32x4 s1[8];
        __builtin_amdgcn_s_setprio(1);
        #pragma unroll
        for (int tn = 0; tn < 8; ++tn) {
            f32x4 z = {};
            #pragma unroll
            for (int kc = 0; kc < 2; ++kc) {
                const bf8 kf = *(const bf8*)&KVs[((tn << 1) + kc) * 512 + L * 8];
                z = __builtin_amdgcn_mfma_f32_16x16x32_bf16(qn[kc], kf, z, 0, 0, 0);
            }
            s1[tn] = z;
        }
        __builtin_amdgcn_s_setprio(0);

        // ---- logits + mask + p = exp(logit - 4); per-lane partial sums ----
        #pragma unroll
        for (int tn = 0; tn < 8; ++tn) {
            const int cl = tn * 16 + l15;
            #pragma unroll
            for (int r = 0; r < 4; ++r) {
                const int row = quad * 4 + r;
                float v = s1[tn][r] + b2f(S2l[row * 148 + (row - cl + 127)]);
                if (cl > diff + w * 16 + row) v = -1e30f;
                float p = __expf(v - 4.0f);       // masked -> 0
                s1[tn][r] = p;
                lsum[r] += p;
            }
        }

        // ---- scatter P in MFMA A-layout (clobbers dead S2l region) ----
        #pragma unroll
        for (int tn = 0; tn < 8; ++tn) {
            const int cl = tn * 16 + l15;
            #pragma unroll
            for (int r = 0; r < 4; ++r) {
                const int row = quad * 4 + r;
                Pl[((cl >> 5) << 9) + (((cl >> 3) & 3) << 7) + (row << 3) + (cl & 7)]
                    = f2b(s1[tn][r]);
            }
        }
        // ---- read P fragments (in-order DS: reads precede overlay writes) ----
        bf8 pa[4];
        #pragma unroll
        for (int kc = 0; kc < 4; ++kc) pa[kc] = ((const bf8*)Pl)[kc * 64 + L];

        // ---- rebuild overlay as sheared P' (zero pads, then scatter) ----
        #pragma unroll
        for (int i = 0; i < 5; ++i)
            ((uint4*)Ppl)[i * 64 + L] = make_uint4(0, 0, 0, 0);
        #pragma unroll
        for (int tn = 0; tn < 8; ++tn) {
            const int cl = tn * 16 + l15;
            #pragma unroll
            for (int r = 0; r < 4; ++r) {
                const int row = quad * 4 + r;
                const int dc = (w & 1) * 16 + row - cl + 127;   // [0,158]
                Ppl[((dc >> 5) << 9) + (((dc >> 3) & 3) << 7) + (row << 3) + (dc & 7)]
                    = f2b(s1[tn][r]);
            }
        }

        __syncthreads();    // bar3: V visible to all waves (drain ~free, V landed)
        __builtin_amdgcn_sched_barrier(0);

        // ---- O += P @ V (V frags from LDS) ----
        __builtin_amdgcn_s_setprio(1);
        {
            #pragma unroll
            for (int tn = 0; tn < 4; ++tn) {
                #pragma unroll
                for (int kc = 0; kc < 4; ++kc) {
                    const bf8 vf = *(const bf8*)&KVs[8192 + (tn * 4 + kc) * 512 + L * 8];
                    o[tn] = __builtin_amdgcn_mfma_f32_16x16x32_bf16(
                        pa[kc], vf, o[tn], 0, 0, 0);
                }
            }
        }
        // ---- O += P' @ EV (global EVP stream) ----
        {
            bf8 pb[5];
            #pragma unroll
            for (int kc = 0; kc < 5; ++kc) pb[kc] = ((const bf8*)Ppl)[kc * 64 + L];
            const int eb = (diff >> 5) + (w >> 1);
            #pragma unroll
            for (int tn = 0; tn < 4; ++tn) {
                #pragma unroll
                for (int kc = 0; kc < 5; ++kc)
                    o[tn] = __builtin_amdgcn_mfma_f32_16x16x32_bf16(
                        pb[kc], EVPF[(tn * 36 + eb + kc) * 64 + L], o[tn], 0, 0, 0);
            }
        }
        __builtin_amdgcn_s_setprio(0);
    }
    flush(t);
}

// ---------------- combine partial (o, lsum) slots for split tiles, normalize -------
__global__ __launch_bounds__(256) void attn_reduce(const float* __restrict__ po,
                                                   const float* __restrict__ lsp,
                                                   u16* __restrict__ yb) {
    const int gi = blockIdx.x;                    // 0 -> tile 4, i -> tile i+7
    const int t = (gi == 0) ? 4 : (gi + 7);
    const int bh = blockIdx.y, b = bh >> 4, h = bh & 15;
    const int ns = (t == 12) ? 3 : 2;
    const size_t base = (size_t)(bh * 19 + d_SB[t]);
    const float* pob = po + (base << 12);
    const float* lsb = lsp + (base << 6);
    #pragma unroll 1
    for (int i = 0; i < 16; ++i) {
        const int idx = i * 256 + threadIdx.x;
        const int row = idx >> 6, col = idx & 63;
        float acc = 0.f, lacc = 0.f;
        for (int s = 0; s < ns; ++s) {
            acc  += pob[(s << 12) + idx];
            lacc += lsb[(s << 6) + row];
        }
        yb[(size_t)(b * 1024 + t * 64 + row) * 1024 + h * 64 + col] = f2b(acc / lacc);
    }
}

extern "C" void kernel_launch(void* const* d_in, const int* in_sizes, int n_in,
                              void* d_out, int out_size, void* d_ws, size_t ws_size,
                              hipStream_t stream) {
    const float* x      = (const float*)d_in[0];
    const float* w_attn = (const float*)d_in[1];
    const float* w_proj = (const float*)d_in[2];
    const float* embk   = (const float*)d_in[3];
    const float* embv   = (const float*)d_in[4];
    float* out = (float*)d_out;

    u16* wsb   = (u16*)d_ws;
    u16* qkvb  = wsb;                  // 4096*3072 (only Q cols live now)
    u16* xb    = qkvb + 12582912;      // 4096*1024            = 4194304
    u16* ymidb = xb;                   // aliases xb (xb dead after gemm1)
    u16* waT   = xb + 4194304;         // 3072*1024            = 3145728
    u16* wpT   = waT + 3145728;        // 1024*1024            = 1048576
    u16* Vt    = wpT + 1048576;        // (slot unused; layout kept stable)
    u16* Kp    = Vt + 4194304;         // 64*64*2*512          = 4194304
    u16* Vp    = Kp + 4194304;         // 64*4*32*512          = 4194304
    u16* EKP   = Vp + 4194304;         // 72*2*512             = 73728
    u16* EVP   = EKP + 73728;          // 4*36*512             = 73728
    float* po  = (float*)(EVP + 73728);// 64*19*4096 f32       = 4980736 f32
    float* lsp = po + 4980736;         // 64*19*64 f32         = 77824 f32

    prep_all<<<dim3(5192), 256, 0, stream>>>(x, embk, embv, w_attn, w_proj,
                                             xb, EKP, EVP, waT, wpT);
    gemm_mfma<u16><<<dim3(24, 32), 256, 0, stream>>>(xb, waT, qkvb, Kp, Vp,
                                                     4096, 3072, 1024);
    attn_mfma<<<dim3(18, 64), 256, 0, stream>>>(qkvb, Kp, Vp, EKP, EVP, ymidb, po, lsp);
    attn_reduce<<<dim3(9, 64), 256, 0, stream>>>(po, lsp, ymidb);
    gemm_mfma64x64<float><<<dim3(16, 64), 256, 0, stream>>>(ymidb, wpT, out, 4096, 1024, 1024);
}

// Round 17
// 235.233 us; speedup vs baseline: 1.0057x; 1.0057x over previous
//
#include <hip/hip_runtime.h>
#include <math.h>

typedef unsigned short u16;
typedef short bf8 __attribute__((ext_vector_type(8)));      // 8 bf16 (raw bits)
typedef float f32x4 __attribute__((ext_vector_type(4)));

__device__ __forceinline__ u16 f2b(float f) {
    union { float f; unsigned u; } x; x.f = f;
    return (u16)((x.u + 0x7FFFu + ((x.u >> 16) & 1u)) >> 16);   // RTNE
}
__device__ __forceinline__ float b2f(u16 b) {
    union { unsigned u; float f; } x; x.u = ((unsigned)b) << 16;
    return x.f;
}

__device__ __forceinline__ void async16(const void* g, void* l) {
    __builtin_amdgcn_global_load_lds(
        (const __attribute__((address_space(1))) unsigned int*)g,
        (__attribute__((address_space(3))) unsigned int*)l, 16, 0, 0);
}

__device__ __forceinline__ void cstore(float* p, float v) { *p = v; }
__device__ __forceinline__ void cstore(u16* p, float v) { *p = f2b(v); }

// ---------------- bf16 MFMA GEMM (m97 structure): C[M,N] = A[M,K] @ Bt[N,K]^T ------
// BK=32 (R12: BK=64 regressed — barrier drain scales with bytes, not count).
// R14 K-FUSION (neutral but harmless, kept): K-blocks (col0 in [1024,2048))
// write scaled fragments straight to Kp; f2b(acc*0.125) bit-identical to the
// old round->scale->round chain (power-of-2 scale).
// R15 V-FUSION (WIN, -6us): V-blocks (col0 >= 2048) transpose acc through a
// 32KB LDS tile (reusing As/Bs — dead after the K-loop's trailing barrier)
// and emit Vp fragments directly; pack_v kernel deleted. Fragment map
// verified vs pack_v; bit-identical. qkvb V region dead (only Q cols live).
template<typename OutT>
__global__ __launch_bounds__(256) void gemm_mfma(const u16* __restrict__ A,
                                                 const u16* __restrict__ Bt,
                                                 OutT* __restrict__ C,
                                                 u16* __restrict__ KP,
                                                 u16* __restrict__ VP,
                                                 int M, int N, int K) {
    __shared__ __align__(16) u16 sh[128 * 128];    // K-loop: As=[0,4096) Bs=[4096,8192); epilogue: ts[128][128]
    u16* As = sh;
    u16* Bs = sh + 128 * 32;
    const int tid = threadIdx.x;
    const int w = tid >> 6, L = tid & 63;
    const int l15 = L & 15, quad = L >> 4;
    const int wm = (w >> 1) * 64, wn = (w & 1) * 64;
    const int row0 = blockIdx.y * 128, col0 = blockIdx.x * 128;
    const int laneRow = L >> 2, laneCol8 = (L & 3) * 8;

    f32x4 acc[4][4] = {};

    for (int k0 = 0; k0 < K; k0 += 32) {
        #pragma unroll
        for (int i = 0; i < 2; ++i) {
            const int seg = w * 2 + i;
            const int r = seg * 16 + laneRow;
            async16(&A[(size_t)(row0 + r) * K + k0 + laneCol8], &As[seg * 512 + L * 8]);
        }
        #pragma unroll
        for (int i = 0; i < 2; ++i) {
            const int seg = w * 2 + i;
            const int r = seg * 16 + laneRow;
            async16(&Bt[(size_t)(col0 + r) * K + k0 + laneCol8], &Bs[seg * 512 + L * 8]);
        }
        __syncthreads();
        bf8 a[4], b[4];
        #pragma unroll
        for (int mt = 0; mt < 4; ++mt)
            a[mt] = *(const bf8*)&As[(wm + mt * 16 + l15) * 32 + quad * 8];
        #pragma unroll
        for (int nt = 0; nt < 4; ++nt)
            b[nt] = *(const bf8*)&Bs[(wn + nt * 16 + l15) * 32 + quad * 8];
        #pragma unroll
        for (int mt = 0; mt < 4; ++mt)
            #pragma unroll
            for (int nt = 0; nt < 4; ++nt)
                acc[mt][nt] = __builtin_amdgcn_mfma_f32_16x16x32_bf16(
                    a[mt], b[nt], acc[mt][nt], 0, 0, 0);
        __syncthreads();
    }
    if (VP != nullptr && col0 >= 2048) {
        // V-block: transpose through LDS, emit Vp fragments (pack_v fused here)
        u16* ts = sh;                              // [s_local][hl*64 + d], 128x128
        #pragma unroll
        for (int mt = 0; mt < 4; ++mt)
            #pragma unroll
            for (int nt = 0; nt < 4; ++nt) {
                const int cloc = wn + nt * 16 + l15;
                #pragma unroll
                for (int r = 0; r < 4; ++r) {
                    const int rloc = wm + mt * 16 + quad * 4 + r;
                    ts[rloc * 128 + cloc] = f2b(acc[mt][nt][r]);
                }
            }
        __syncthreads();
        const int b = row0 >> 10;
        const int h0 = (col0 - 2048) >> 6;
        const int c32base = (row0 >> 5) & 31;
        #pragma unroll
        for (int j = 0; j < 8; ++j) {
            const int f = j * 256 + tid;           // frag id in [0, 2048)
            const int hl = f >> 10, tn2 = (f >> 8) & 3, c32l = (f >> 6) & 3;
            const int Lf = f & 63, l15f = f & 15, quadf = (f >> 4) & 3;
            __align__(16) u16 buf[8];
            #pragma unroll
            for (int i = 0; i < 8; ++i)
                buf[i] = ts[(c32l * 32 + quadf * 8 + i) * 128 + hl * 64 + tn2 * 16 + l15f];
            const int bh = (b << 4) + h0 + hl;
            *(uint4*)(VP + ((size_t)(bh * 8192 + tn2 * 2048 + (c32base + c32l) * 64 + Lf) << 3))
                = *(uint4*)buf;
        }
    } else if (KP != nullptr && col0 >= 1024) {
        // K-block: emit fragment-linear Kp (pre-scaled by 1/8)
        #pragma unroll
        for (int mt = 0; mt < 4; ++mt)
            #pragma unroll
            for (int nt = 0; nt < 4; ++nt) {
                const int hd = col0 - 1024 + wn + nt * 16 + l15;
                const int h = hd >> 6, d = hd & 63;
                const int doff = ((d >> 5) << 6) + (((d >> 3) & 3) << 4);
                #pragma unroll
                for (int r = 0; r < 4; ++r) {
                    const int row = row0 + wm + mt * 16 + quad * 4 + r;
                    const int b = row >> 10, s = row & 1023;
                    const size_t idx =
                        ((size_t)((((b << 4) + h) << 13) + ((s >> 4) << 7) + doff + (s & 15)) << 3)
                        + (d & 7);
                    KP[idx] = f2b(acc[mt][nt][r] * 0.125f);
                }
            }
    } else {
        #pragma unroll
        for (int mt = 0; mt < 4; ++mt)
            #pragma unroll
            for (int nt = 0; nt < 4; ++nt) {
                const int col = col0 + wn + nt * 16 + l15;
                #pragma unroll
                for (int r = 0; r < 4; ++r) {
                    const int row = row0 + wm + mt * 16 + quad * 4 + r;
                    cstore(&C[(size_t)row * N + col], acc[mt][nt][r]);
                }
            }
    }
}

// ---------------- 64x128-tile variant (gemm2): 2 blocks/CU — the optimum ----------
// Block-count ladder bracketed: 128x128 @1 blk/CU slow (pre-R7), 64x128
// @2 blk/CU best (R7/R15: 233.7us), 64x64 @4 blk/CU worse (R16: +3us —
// doubled staging traffic + halved MFMA-per-barrier outweigh residency).
// BK=32 (R12: BK=64 regressed).
template<typename OutT>
__global__ __launch_bounds__(256) void gemm_mfma64(const u16* __restrict__ A,
                                                   const u16* __restrict__ Bt,
                                                   OutT* __restrict__ C,
                                                   int M, int N, int K) {
    __shared__ __align__(16) u16 As[64 * 32];
    __shared__ __align__(16) u16 Bs[128 * 32];
    const int tid = threadIdx.x;
    const int w = tid >> 6, L = tid & 63;
    const int l15 = L & 15, quad = L >> 4;
    const int wm = (w >> 1) * 32, wn = (w & 1) * 64;
    const int row0 = blockIdx.y * 64, col0 = blockIdx.x * 128;
    const int laneRow = L >> 2, laneCol8 = (L & 3) * 8;

    f32x4 acc[2][4] = {};

    for (int k0 = 0; k0 < K; k0 += 32) {
        {   // A: 64x32 = 256 chunks, one per thread (seg = w)
            const int r = w * 16 + laneRow;
            async16(&A[(size_t)(row0 + r) * K + k0 + laneCol8], &As[w * 512 + L * 8]);
        }
        #pragma unroll
        for (int i = 0; i < 2; ++i) {   // B: 128x32 = 512 chunks, two per thread
            const int seg = w * 2 + i;
            const int r = seg * 16 + laneRow;
            async16(&Bt[(size_t)(col0 + r) * K + k0 + laneCol8], &Bs[seg * 512 + L * 8]);
        }
        __syncthreads();
        bf8 a[2], b[4];
        #pragma unroll
        for (int mt = 0; mt < 2; ++mt)
            a[mt] = *(const bf8*)&As[(wm + mt * 16 + l15) * 32 + quad * 8];
        #pragma unroll
        for (int nt = 0; nt < 4; ++nt)
            b[nt] = *(const bf8*)&Bs[(wn + nt * 16 + l15) * 32 + quad * 8];
        #pragma unroll
        for (int mt = 0; mt < 2; ++mt)
            #pragma unroll
            for (int nt = 0; nt < 4; ++nt)
                acc[mt][nt] = __builtin_amdgcn_mfma_f32_16x16x32_bf16(
                    a[mt], b[nt], acc[mt][nt], 0, 0, 0);
        __syncthreads();
    }
    #pragma unroll
    for (int mt = 0; mt < 2; ++mt)
        #pragma unroll
        for (int nt = 0; nt < 4; ++nt) {
            const int col = col0 + wn + nt * 16 + l15;
            #pragma unroll
            for (int r = 0; r < 4; ++r) {
                const int row = row0 + wm + mt * 16 + quad * 4 + r;
                cstore(&C[(size_t)row * N + col], acc[mt][nt][r]);
            }
        }
}

// ---------------- merged prep: x->bf16, EKP/EVP fragment tables, weight transposes --
__global__ __launch_bounds__(256) void prep_all(const float* __restrict__ x,
                                                const float* __restrict__ embk,
                                                const float* __restrict__ embv,
                                                const float* __restrict__ w_attn,
                                                const float* __restrict__ w_proj,
                                                u16* __restrict__ xb,
                                                u16* __restrict__ EKP,
                                                u16* __restrict__ EVP,
                                                u16* __restrict__ waT,
                                                u16* __restrict__ wpT) {
    __shared__ u16 ts[64][65];
    const int bx = blockIdx.x;
    const int tid = threadIdx.x;
    if (bx < 4096) {
        int idx = bx * 256 + tid;
        const float4 v = ((const float4*)x)[idx];
        ((ushort4*)xb)[idx] = make_ushort4(f2b(v.x), f2b(v.y), f2b(v.z), f2b(v.w));
    } else if (bx < 4132) {
        int t = (bx - 4096) * 256 + tid;           // [0, 9216)
        int L = t & 63, kc = (t >> 6) & 1, k16 = t >> 7;
        int l15 = L & 15, quad = L >> 4;
        int row = 1 + k16 * 16 + l15;
        int d = row - 128;
        int cl = d < 0 ? 0 : (d > 1023 ? 1023 : d);
        const float* p = embk + cl * 64 + kc * 32 + quad * 8;
        #pragma unroll
        for (int i = 0; i < 8; ++i) EKP[t * 8 + i] = f2b(p[i]);
    } else if (bx < 4168) {
        int t = (bx - 4132) * 256 + tid;           // [0, 9216)
        int L = t & 63, rest = t >> 6;             // rest = tn*36 + c32
        int c32 = rest % 36, tn = rest / 36;
        int l15 = L & 15, quad = L >> 4;
        #pragma unroll
        for (int i = 0; i < 8; ++i) {
            int c = c32 * 32 + quad * 8 + i;
            int d = c - 127;
            int cl = d < 0 ? 0 : (d > 1023 ? 1023 : d);
            EVP[t * 8 + i] = f2b(embv[cl * 64 + tn * 16 + l15]);
        }
    } else {
        const float* W; u16* WT; int Cc, t;
        if (bx < 4168 + 768) { t = bx - 4168; W = w_attn; WT = waT; Cc = 3072; }
        else                 { t = bx - 4936; W = w_proj; WT = wpT; Cc = 1024; }
        const int nx = Cc >> 6;
        const int c0 = (t % nx) * 64, r0 = (t / nx) * 64;
        for (int i = tid; i < 4096; i += 256) {
            int r = i >> 6, c = i & 63;
            ts[r][c] = f2b(W[(size_t)(r0 + r) * Cc + c0 + c]);
        }
        __syncthreads();
        for (int i = tid; i < 4096; i += 256) {
            int c = i >> 6, r = i & 63;
            WT[(size_t)(c0 + c) * 1024 + r0 + r] = ts[r][c];
        }
    }
}

// cumulative chunk counts: tile t owns units [S(t), S(t)+t/2+1); S(16)=72 total.
__device__ const int d_S[17] = {0,1,2,4,6,9,12,16,20,25,30,36,42,49,56,64,72};
// partial-slot base per split tile (tiles 4, 8..15), compact: 19 slots per bh.
// tile:       0  1  2  3  4  5  6  7  8  9 10 11 12 13 14 15
__device__ const int d_SB[16] = {0,0,0,0, 0,0,0,0, 2, 4, 6, 8,10,13,15,17};

// ---------------- MFMA fused attention with RPE: split-barrier staged pipeline -----
// grid (18, 64), unit-split (R6). R8 schedule — PROVEN 81-97us (session band):
//   bar1 = __syncthreads (drain ~free) -> issue K DMA -> S2 EKP stream covers
//   K latency -> [sched_barrier] -> issue V DMA LAST -> asm vmcnt(4) waits
//   ONLY the 4 older K-DMAs/thread (V stays in flight) -> raw s_barrier ->
//   S1 consumes K while V's latency hides under softmax+scatter -> bar3 =
//   __syncthreads (drain ~free, V landed) -> PV + P'EV. s_setprio(1) wraps
//   MFMA clusters (attn +4-7%, m191).
// R9/R10 LESSON: deeper cross-unit pipelining inflated VGPR 124->148, dropped
// occupancy 16.5->10.2%, DOUBLED attn time. Occupancy >= scheduling here —
// keep this body register-lean. Plain __launch_bounds__(256): min-waves hints
// force spills (R3/R4). Direct-global K/V loses 25-60% (R1/R5) — keep staging.
__global__ __launch_bounds__(256) void attn_mfma(const u16* __restrict__ qkvb,
                                                 const u16* __restrict__ Kp,
                                                 const u16* __restrict__ Vp,
                                                 const u16* __restrict__ EKP,
                                                 const u16* __restrict__ EVP,
                                                 u16* __restrict__ yb,
                                                 float* __restrict__ po,
                                                 float* __restrict__ lsp) {
    __shared__ __align__(16) u16 slab_[4][2560];   // 20480 B, per-wave overlay
    __shared__ __align__(16) u16 KVs[16384];       // 32768 B: K [0..8192), V [8192..)

    const int tid = threadIdx.x;
    const int w = tid >> 6, L = tid & 63;
    const int l15 = L & 15, quad = L >> 4;
    const int blk = blockIdx.x;
    const int bh = blockIdx.y, b = bh >> 4, h = bh & 15;
    u16* S2l = slab_[w];
    u16* Pl  = slab_[w];
    u16* Ppl = slab_[w];

    const bf8* EKPF = (const bf8*)EKP;
    const bf8* EVPF = (const bf8*)EVP;

    bf8 qn[2];
    f32x4 o[4];
    float lsum[4];
    int t = -1, t0 = 0;

    auto flush = [&](int tt) {
        float lr[4];
        #pragma unroll
        for (int r = 0; r < 4; ++r) {
            float s = lsum[r];
            s += __shfl_xor(s, 1); s += __shfl_xor(s, 2);
            s += __shfl_xor(s, 4); s += __shfl_xor(s, 8);
            lr[r] = s;
        }
        const bool whole = (d_S[tt] >> 2) == ((d_S[tt + 1] - 1) >> 2);
        if (whole) {           // all units of this tile in this block: finalize
            #pragma unroll
            for (int tn = 0; tn < 4; ++tn) {
                const int col = h * 64 + tn * 16 + l15;
                #pragma unroll
                for (int r = 0; r < 4; ++r) {
                    const int trow = tt * 64 + w * 16 + quad * 4 + r;
                    yb[(size_t)(b * 1024 + trow) * 1024 + col] = f2b(o[tn][r] / lr[r]);
                }
            }
        } else {               // partial: statically-indexed slot
            const int slot = blk - (d_S[tt] >> 2);
            const size_t sidx = (size_t)(bh * 19 + d_SB[tt] + slot);
            float* pob = po + (sidx << 12);
            #pragma unroll
            for (int tn = 0; tn < 4; ++tn)
                #pragma unroll
                for (int r = 0; r < 4; ++r)
                    pob[(w * 16 + quad * 4 + r) * 64 + tn * 16 + l15] = o[tn][r];
            if (l15 == 0) {
                float* lsb = lsp + (sidx << 6);
                #pragma unroll
                for (int r = 0; r < 4; ++r) lsb[w * 16 + quad * 4 + r] = lr[r];
            }
        }
    };

    #pragma unroll 1
    for (int ui = 0; ui < 4; ++ui) {
        const int u = blk * 4 + ui;
        int nt = (t < 0) ? 0 : t;
        while (d_S[nt + 1] <= u) ++nt;
        if (nt != t) {
            if (t >= 0) flush(t);
            t = nt; t0 = t * 64;
            const int trow = t0 + w * 16 + l15;
            const u16* qp = qkvb + (size_t)(b * 1024 + trow) * 3072 + h * 64 + quad * 8;
            qn[0] = *(const bf8*)qp;
            qn[1] = *(const bf8*)(qp + 32);
            #pragma unroll
            for (int tn = 0; tn < 4; ++tn)
                #pragma unroll
                for (int j = 0; j < 4; ++j) o[tn][j] = 0.f;
            #pragma unroll
            for (int r = 0; r < 4; ++r) lsum[r] = 0.f;
        }
        const int c = u - d_S[t];
        const int s0 = c << 7;
        const int diff = t0 - s0;                 // >= 0, multiple of 64

        __syncthreads();    // bar1: prior unit's LDS reads retired (drain ~free)

        // ---- issue K DMA only (16 KB contiguous) ----
        {
            const size_t kbase = ((size_t)(bh * 64 + (s0 >> 4)) << 1) * 512;
            #pragma unroll
            for (int i = 0; i < 4; ++i)
                async16(Kp + kbase + (i * 256 + tid) * 8, &KVs[(i * 256 + tid) * 8]);
        }

        // ---- S2 = Q @ EK^T (global EKP stream; covers K DMA latency) ----
        f32x4 s2[9] = {};
        {
            const int kb = (diff >> 4) + w;       // k16 base
            #pragma unroll
            for (int j = 0; j < 9; ++j) {
                #pragma unroll
                for (int kc = 0; kc < 2; ++kc)
                    s2[j] = __builtin_amdgcn_mfma_f32_16x16x32_bf16(
                        qn[kc], EKPF[(((kb + j) << 1) + kc) * 64 + L], s2[j], 0, 0, 0);
            }
        }
        #pragma unroll
        for (int j = 0; j < 9; ++j)
            #pragma unroll
            for (int r = 0; r < 4; ++r)
                S2l[(quad * 4 + r) * 148 + j * 16 + l15] = f2b(s2[j][r]);

        // ---- issue V DMA LAST (latency hides under S1 + softmax + scatter) ----
        __builtin_amdgcn_sched_barrier(0);   // pin V issue after all S2 loads
        {
            const int vb = bh * 128 + (s0 >> 5);
            #pragma unroll
            for (int i = 0; i < 4; ++i)
                async16(Vp + ((size_t)(vb + i * 32) * 512 + tid * 8),
                        &KVs[8192 + i * 2048 + tid * 8]);
        }

        // ---- wait K only (4 oldest VMEM; V stays in flight), rendezvous ----
        asm volatile("s_waitcnt vmcnt(4)" ::: "memory");
        __builtin_amdgcn_s_barrier();
        __builtin_amdgcn_sched_barrier(0);

        // ---- S1 = Q @ (K/8)^T from LDS ----
        f32x4 s1[8];
        __builtin_amdgcn_s_setprio(1);
        #pragma unroll
        for (int tn = 0; tn < 8; ++tn) {
            f32x4 z = {};
            #pragma unroll
            for (int kc = 0; kc < 2; ++kc) {
                const bf8 kf = *(const bf8*)&KVs[((tn << 1) + kc) * 512 + L * 8];
                z = __builtin_amdgcn_mfma_f32_16x16x32_bf16(qn[kc], kf, z, 0, 0, 0);
            }
            s1[tn] = z;
        }
        __builtin_amdgcn_s_setprio(0);

        // ---- logits + mask + p = exp(logit - 4); per-lane partial sums ----
        #pragma unroll
        for (int tn = 0; tn < 8; ++tn) {
            const int cl = tn * 16 + l15;
            #pragma unroll
            for (int r = 0; r < 4; ++r) {
                const int row = quad * 4 + r;
                float v = s1[tn][r] + b2f(S2l[row * 148 + (row - cl + 127)]);
                if (cl > diff + w * 16 + row) v = -1e30f;
                float p = __expf(v - 4.0f);       // masked -> 0
                s1[tn][r] = p;
                lsum[r] += p;
            }
        }

        // ---- scatter P in MFMA A-layout (clobbers dead S2l region) ----
        #pragma unroll
        for (int tn = 0; tn < 8; ++tn) {
            const int cl = tn * 16 + l15;
            #pragma unroll
            for (int r = 0; r < 4; ++r) {
                const int row = quad * 4 + r;
                Pl[((cl >> 5) << 9) + (((cl >> 3) & 3) << 7) + (row << 3) + (cl & 7)]
                    = f2b(s1[tn][r]);
            }
        }
        // ---- read P fragments (in-order DS: reads precede overlay writes) ----
        bf8 pa[4];
        #pragma unroll
        for (int kc = 0; kc < 4; ++kc) pa[kc] = ((const bf8*)Pl)[kc * 64 + L];

        // ---- rebuild overlay as sheared P' (zero pads, then scatter) ----
        #pragma unroll
        for (int i = 0; i < 5; ++i)
            ((uint4*)Ppl)[i * 64 + L] = make_uint4(0, 0, 0, 0);
        #pragma unroll
        for (int tn = 0; tn < 8; ++tn) {
            const int cl = tn * 16 + l15;
            #pragma unroll
            for (int r = 0; r < 4; ++r) {
                const int row = quad * 4 + r;
                const int dc = (w & 1) * 16 + row - cl + 127;   // [0,158]
                Ppl[((dc >> 5) << 9) + (((dc >> 3) & 3) << 7) + (row << 3) + (dc & 7)]
                    = f2b(s1[tn][r]);
            }
        }

        __syncthreads();    // bar3: V visible to all waves (drain ~free, V landed)
        __builtin_amdgcn_sched_barrier(0);

        // ---- O += P @ V (V frags from LDS) ----
        __builtin_amdgcn_s_setprio(1);
        {
            #pragma unroll
            for (int tn = 0; tn < 4; ++tn) {
                #pragma unroll
                for (int kc = 0; kc < 4; ++kc) {
                    const bf8 vf = *(const bf8*)&KVs[8192 + (tn * 4 + kc) * 512 + L * 8];
                    o[tn] = __builtin_amdgcn_mfma_f32_16x16x32_bf16(
                        pa[kc], vf, o[tn], 0, 0, 0);
                }
            }
        }
        // ---- O += P' @ EV (global EVP stream) ----
        {
            bf8 pb[5];
            #pragma unroll
            for (int kc = 0; kc < 5; ++kc) pb[kc] = ((const bf8*)Ppl)[kc * 64 + L];
            const int eb = (diff >> 5) + (w >> 1);
            #pragma unroll
            for (int tn = 0; tn < 4; ++tn) {
                #pragma unroll
                for (int kc = 0; kc < 5; ++kc)
                    o[tn] = __builtin_amdgcn_mfma_f32_16x16x32_bf16(
                        pb[kc], EVPF[(tn * 36 + eb + kc) * 64 + L], o[tn], 0, 0, 0);
            }
        }
        __builtin_amdgcn_s_setprio(0);
    }
    flush(t);
}

// ---------------- combine partial (o, lsum) slots for split tiles, normalize -------
__global__ __launch_bounds__(256) void attn_reduce(const float* __restrict__ po,
                                                   const float* __restrict__ lsp,
                                                   u16* __restrict__ yb) {
    const int gi = blockIdx.x;                    // 0 -> tile 4, i -> tile i+7
    const int t = (gi == 0) ? 4 : (gi + 7);
    const int bh = blockIdx.y, b = bh >> 4, h = bh & 15;
    const int ns = (t == 12) ? 3 : 2;
    const size_t base = (size_t)(bh * 19 + d_SB[t]);
    const float* pob = po + (base << 12);
    const float* lsb = lsp + (base << 6);
    #pragma unroll 1
    for (int i = 0; i < 16; ++i) {
        const int idx = i * 256 + threadIdx.x;
        const int row = idx >> 6, col = idx & 63;
        float acc = 0.f, lacc = 0.f;
        for (int s = 0; s < ns; ++s) {
            acc  += pob[(s << 12) + idx];
            lacc += lsb[(s << 6) + row];
        }
        yb[(size_t)(b * 1024 + t * 64 + row) * 1024 + h * 64 + col] = f2b(acc / lacc);
    }
}

extern "C" void kernel_launch(void* const* d_in, const int* in_sizes, int n_in,
                              void* d_out, int out_size, void* d_ws, size_t ws_size,
                              hipStream_t stream) {
    const float* x      = (const float*)d_in[0];
    const float* w_attn = (const float*)d_in[1];
    const float* w_proj = (const float*)d_in[2];
    const float* embk   = (const float*)d_in[3];
    const float* embv   = (const float*)d_in[4];
    float* out = (float*)d_out;

    u16* wsb   = (u16*)d_ws;
    u16* qkvb  = wsb;                  // 4096*3072 (only Q cols live now)
    u16* xb    = qkvb + 12582912;      // 4096*1024            = 4194304
    u16* ymidb = xb;                   // aliases xb (xb dead after gemm1)
    u16* waT   = xb + 4194304;         // 3072*1024            = 3145728
    u16* wpT   = waT + 3145728;        // 1024*1024            = 1048576
    u16* Vt    = wpT + 1048576;        // (slot unused; layout kept stable)
    u16* Kp    = Vt + 4194304;         // 64*64*2*512          = 4194304
    u16* Vp    = Kp + 4194304;         // 64*4*32*512          = 4194304
    u16* EKP   = Vp + 4194304;         // 72*2*512             = 73728
    u16* EVP   = EKP + 73728;          // 4*36*512             = 73728
    float* po  = (float*)(EVP + 73728);// 64*19*4096 f32       = 4980736 f32
    float* lsp = po + 4980736;         // 64*19*64 f32         = 77824 f32

    prep_all<<<dim3(5192), 256, 0, stream>>>(x, embk, embv, w_attn, w_proj,
                                             xb, EKP, EVP, waT, wpT);
    gemm_mfma<u16><<<dim3(24, 32), 256, 0, stream>>>(xb, waT, qkvb, Kp, Vp,
                                                     4096, 3072, 1024);
    attn_mfma<<<dim3(18, 64), 256, 0, stream>>>(qkvb, Kp, Vp, EKP, EVP, ymidb, po, lsp);
    attn_reduce<<<dim3(9, 64), 256, 0, stream>>>(po, lsp, ymidb);
    gemm_mfma64<float><<<dim3(8, 64), 256, 0, stream>>>(ymidb, wpT, out, 4096, 1024, 1024);
}

// Round 18
// 232.946 us; speedup vs baseline: 1.0156x; 1.0098x over previous
//
#include <hip/hip_runtime.h>
#include <math.h>

typedef unsigned short u16;
typedef short bf8 __attribute__((ext_vector_type(8)));      // 8 bf16 (raw bits)
typedef float f32x4 __attribute__((ext_vector_type(4)));

__device__ __forceinline__ u16 f2b(float f) {
    union { float f; unsigned u; } x; x.f = f;
    return (u16)((x.u + 0x7FFFu + ((x.u >> 16) & 1u)) >> 16);   // RTNE
}
__device__ __forceinline__ float b2f(u16 b) {
    union { unsigned u; float f; } x; x.u = ((unsigned)b) << 16;
    return x.f;
}

__device__ __forceinline__ void async16(const void* g, void* l) {
    __builtin_amdgcn_global_load_lds(
        (const __attribute__((address_space(1))) unsigned int*)g,
        (__attribute__((address_space(3))) unsigned int*)l, 16, 0, 0);
}

__device__ __forceinline__ void cstore(float* p, float v) { *p = v; }
__device__ __forceinline__ void cstore(u16* p, float v) { *p = f2b(v); }

// ---------------- bf16 MFMA GEMM (m97 structure): C[M,N] = A[M,K] @ Bt[N,K]^T ------
// BK=32 (R12: BK=64 regressed — barrier drain scales with bytes, not count).
// R14 K-FUSION (neutral, kept): K-blocks write scaled fragments straight to
// Kp; f2b(acc*0.125) bit-identical (power-of-2 scale).
// R15 V-FUSION (WIN, -6us): V-blocks transpose acc through a 32KB LDS tile
// and emit Vp fragments directly; pack_v kernel deleted. Bit-identical.
template<typename OutT>
__global__ __launch_bounds__(256) void gemm_mfma(const u16* __restrict__ A,
                                                 const u16* __restrict__ Bt,
                                                 OutT* __restrict__ C,
                                                 u16* __restrict__ KP,
                                                 u16* __restrict__ VP,
                                                 int M, int N, int K) {
    __shared__ __align__(16) u16 sh[128 * 128];    // K-loop: As=[0,4096) Bs=[4096,8192); epilogue: ts[128][128]
    u16* As = sh;
    u16* Bs = sh + 128 * 32;
    const int tid = threadIdx.x;
    const int w = tid >> 6, L = tid & 63;
    const int l15 = L & 15, quad = L >> 4;
    const int wm = (w >> 1) * 64, wn = (w & 1) * 64;
    const int row0 = blockIdx.y * 128, col0 = blockIdx.x * 128;
    const int laneRow = L >> 2, laneCol8 = (L & 3) * 8;

    f32x4 acc[4][4] = {};

    for (int k0 = 0; k0 < K; k0 += 32) {
        #pragma unroll
        for (int i = 0; i < 2; ++i) {
            const int seg = w * 2 + i;
            const int r = seg * 16 + laneRow;
            async16(&A[(size_t)(row0 + r) * K + k0 + laneCol8], &As[seg * 512 + L * 8]);
        }
        #pragma unroll
        for (int i = 0; i < 2; ++i) {
            const int seg = w * 2 + i;
            const int r = seg * 16 + laneRow;
            async16(&Bt[(size_t)(col0 + r) * K + k0 + laneCol8], &Bs[seg * 512 + L * 8]);
        }
        __syncthreads();
        bf8 a[4], b[4];
        #pragma unroll
        for (int mt = 0; mt < 4; ++mt)
            a[mt] = *(const bf8*)&As[(wm + mt * 16 + l15) * 32 + quad * 8];
        #pragma unroll
        for (int nt = 0; nt < 4; ++nt)
            b[nt] = *(const bf8*)&Bs[(wn + nt * 16 + l15) * 32 + quad * 8];
        #pragma unroll
        for (int mt = 0; mt < 4; ++mt)
            #pragma unroll
            for (int nt = 0; nt < 4; ++nt)
                acc[mt][nt] = __builtin_amdgcn_mfma_f32_16x16x32_bf16(
                    a[mt], b[nt], acc[mt][nt], 0, 0, 0);
        __syncthreads();
    }
    if (VP != nullptr && col0 >= 2048) {
        // V-block: transpose through LDS, emit Vp fragments (pack_v fused here)
        u16* ts = sh;                              // [s_local][hl*64 + d], 128x128
        #pragma unroll
        for (int mt = 0; mt < 4; ++mt)
            #pragma unroll
            for (int nt = 0; nt < 4; ++nt) {
                const int cloc = wn + nt * 16 + l15;
                #pragma unroll
                for (int r = 0; r < 4; ++r) {
                    const int rloc = wm + mt * 16 + quad * 4 + r;
                    ts[rloc * 128 + cloc] = f2b(acc[mt][nt][r]);
                }
            }
        __syncthreads();
        const int b = row0 >> 10;
        const int h0 = (col0 - 2048) >> 6;
        const int c32base = (row0 >> 5) & 31;
        #pragma unroll
        for (int j = 0; j < 8; ++j) {
            const int f = j * 256 + tid;           // frag id in [0, 2048)
            const int hl = f >> 10, tn2 = (f >> 8) & 3, c32l = (f >> 6) & 3;
            const int Lf = f & 63, l15f = f & 15, quadf = (f >> 4) & 3;
            __align__(16) u16 buf[8];
            #pragma unroll
            for (int i = 0; i < 8; ++i)
                buf[i] = ts[(c32l * 32 + quadf * 8 + i) * 128 + hl * 64 + tn2 * 16 + l15f];
            const int bh = (b << 4) + h0 + hl;
            *(uint4*)(VP + ((size_t)(bh * 8192 + tn2 * 2048 + (c32base + c32l) * 64 + Lf) << 3))
                = *(uint4*)buf;
        }
    } else if (KP != nullptr && col0 >= 1024) {
        // K-block: emit fragment-linear Kp (pre-scaled by 1/8)
        #pragma unroll
        for (int mt = 0; mt < 4; ++mt)
            #pragma unroll
            for (int nt = 0; nt < 4; ++nt) {
                const int hd = col0 - 1024 + wn + nt * 16 + l15;
                const int h = hd >> 6, d = hd & 63;
                const int doff = ((d >> 5) << 6) + (((d >> 3) & 3) << 4);
                #pragma unroll
                for (int r = 0; r < 4; ++r) {
                    const int row = row0 + wm + mt * 16 + quad * 4 + r;
                    const int b = row >> 10, s = row & 1023;
                    const size_t idx =
                        ((size_t)((((b << 4) + h) << 13) + ((s >> 4) << 7) + doff + (s & 15)) << 3)
                        + (d & 7);
                    KP[idx] = f2b(acc[mt][nt][r] * 0.125f);
                }
            }
    } else {
        #pragma unroll
        for (int mt = 0; mt < 4; ++mt)
            #pragma unroll
            for (int nt = 0; nt < 4; ++nt) {
                const int col = col0 + wn + nt * 16 + l15;
                #pragma unroll
                for (int r = 0; r < 4; ++r) {
                    const int row = row0 + wm + mt * 16 + quad * 4 + r;
                    cstore(&C[(size_t)row * N + col], acc[mt][nt][r]);
                }
            }
    }
}

// ---------------- 64x128-tile variant (gemm2): 2 blocks/CU — the optimum ----------
// Bracketed: 128x128 @1 blk/CU slow, 64x128 @2 blk/CU best (R7/R15),
// 64x64 @4 blk/CU worse (R16). BK=32 (R12).
template<typename OutT>
__global__ __launch_bounds__(256) void gemm_mfma64(const u16* __restrict__ A,
                                                   const u16* __restrict__ Bt,
                                                   OutT* __restrict__ C,
                                                   int M, int N, int K) {
    __shared__ __align__(16) u16 As[64 * 32];
    __shared__ __align__(16) u16 Bs[128 * 32];
    const int tid = threadIdx.x;
    const int w = tid >> 6, L = tid & 63;
    const int l15 = L & 15, quad = L >> 4;
    const int wm = (w >> 1) * 32, wn = (w & 1) * 64;
    const int row0 = blockIdx.y * 64, col0 = blockIdx.x * 128;
    const int laneRow = L >> 2, laneCol8 = (L & 3) * 8;

    f32x4 acc[2][4] = {};

    for (int k0 = 0; k0 < K; k0 += 32) {
        {   // A: 64x32 = 256 chunks, one per thread (seg = w)
            const int r = w * 16 + laneRow;
            async16(&A[(size_t)(row0 + r) * K + k0 + laneCol8], &As[w * 512 + L * 8]);
        }
        #pragma unroll
        for (int i = 0; i < 2; ++i) {   // B: 128x32 = 512 chunks, two per thread
            const int seg = w * 2 + i;
            const int r = seg * 16 + laneRow;
            async16(&Bt[(size_t)(col0 + r) * K + k0 + laneCol8], &Bs[seg * 512 + L * 8]);
        }
        __syncthreads();
        bf8 a[2], b[4];
        #pragma unroll
        for (int mt = 0; mt < 2; ++mt)
            a[mt] = *(const bf8*)&As[(wm + mt * 16 + l15) * 32 + quad * 8];
        #pragma unroll
        for (int nt = 0; nt < 4; ++nt)
            b[nt] = *(const bf8*)&Bs[(wn + nt * 16 + l15) * 32 + quad * 8];
        #pragma unroll
        for (int mt = 0; mt < 2; ++mt)
            #pragma unroll
            for (int nt = 0; nt < 4; ++nt)
                acc[mt][nt] = __builtin_amdgcn_mfma_f32_16x16x32_bf16(
                    a[mt], b[nt], acc[mt][nt], 0, 0, 0);
        __syncthreads();
    }
    #pragma unroll
    for (int mt = 0; mt < 2; ++mt)
        #pragma unroll
        for (int nt = 0; nt < 4; ++nt) {
            const int col = col0 + wn + nt * 16 + l15;
            #pragma unroll
            for (int r = 0; r < 4; ++r) {
                const int row = row0 + wm + mt * 16 + quad * 4 + r;
                cstore(&C[(size_t)row * N + col], acc[mt][nt][r]);
            }
        }
}

// ---------------- merged prep: x->bf16, EKP/EVP fragment tables, weight transposes --
__global__ __launch_bounds__(256) void prep_all(const float* __restrict__ x,
                                                const float* __restrict__ embk,
                                                const float* __restrict__ embv,
                                                const float* __restrict__ w_attn,
                                                const float* __restrict__ w_proj,
                                                u16* __restrict__ xb,
                                                u16* __restrict__ EKP,
                                                u16* __restrict__ EVP,
                                                u16* __restrict__ waT,
                                                u16* __restrict__ wpT) {
    __shared__ u16 ts[64][65];
    const int bx = blockIdx.x;
    const int tid = threadIdx.x;
    if (bx < 4096) {
        int idx = bx * 256 + tid;
        const float4 v = ((const float4*)x)[idx];
        ((ushort4*)xb)[idx] = make_ushort4(f2b(v.x), f2b(v.y), f2b(v.z), f2b(v.w));
    } else if (bx < 4132) {
        int t = (bx - 4096) * 256 + tid;           // [0, 9216)
        int L = t & 63, kc = (t >> 6) & 1, k16 = t >> 7;
        int l15 = L & 15, quad = L >> 4;
        int row = 1 + k16 * 16 + l15;
        int d = row - 128;
        int cl = d < 0 ? 0 : (d > 1023 ? 1023 : d);
        const float* p = embk + cl * 64 + kc * 32 + quad * 8;
        #pragma unroll
        for (int i = 0; i < 8; ++i) EKP[t * 8 + i] = f2b(p[i]);
    } else if (bx < 4168) {
        int t = (bx - 4132) * 256 + tid;           // [0, 9216)
        int L = t & 63, rest = t >> 6;             // rest = tn*36 + c32
        int c32 = rest % 36, tn = rest / 36;
        int l15 = L & 15, quad = L >> 4;
        #pragma unroll
        for (int i = 0; i < 8; ++i) {
            int c = c32 * 32 + quad * 8 + i;
            int d = c - 127;
            int cl = d < 0 ? 0 : (d > 1023 ? 1023 : d);
            EVP[t * 8 + i] = f2b(embv[cl * 64 + tn * 16 + l15]);
        }
    } else {
        const float* W; u16* WT; int Cc, t;
        if (bx < 4168 + 768) { t = bx - 4168; W = w_attn; WT = waT; Cc = 3072; }
        else                 { t = bx - 4936; W = w_proj; WT = wpT; Cc = 1024; }
        const int nx = Cc >> 6;
        const int c0 = (t % nx) * 64, r0 = (t / nx) * 64;
        for (int i = tid; i < 4096; i += 256) {
            int r = i >> 6, c = i & 63;
            ts[r][c] = f2b(W[(size_t)(r0 + r) * Cc + c0 + c]);
        }
        __syncthreads();
        for (int i = tid; i < 4096; i += 256) {
            int c = i >> 6, r = i & 63;
            WT[(size_t)(c0 + c) * 1024 + r0 + r] = ts[r][c];
        }
    }
}

// cumulative chunk counts: tile t owns units [S(t), S(t)+t/2+1); S(16)=72 total.
__device__ const int d_S[17] = {0,1,2,4,6,9,12,16,20,25,30,36,42,49,56,64,72};
// partial-slot base per split tile (tiles 4, 8..15), compact: 19 slots per bh.
// tile:       0  1  2  3  4  5  6  7  8  9 10 11 12 13 14 15
__device__ const int d_SB[16] = {0,0,0,0, 0,0,0,0, 2, 4, 6, 8,10,13,15,17};

// ---------------- MFMA fused attention with RPE: split-barrier staged pipeline -----
// R18: XCD-AWARE SWIZZLE (T1). 1D grid 1152; bid -> (bh, blk) via
//   xcd = bid&7, slot = bid>>3, bh = (slot/18)*8 + xcd, blk = slot%18.
// Bijective (1152 = 8 XCDs x 144; 144 = 8 bh-groups x 18 blocks). All 18
// blocks sharing one bh's Kp/Vp/EKP (~1.3MB, re-read 9x) now land on ONE
// XCD's L2; per-XCD concurrent working set ~8 bh = 3MB <= 4MB L2 (was ~16 bh
// = 6MB, spilling K/V DMAs to HBM ~900cyc, escaping the S2 cover window).
// Pure index permutation — correctness unaffected (G16).
// R8 schedule otherwise unchanged (PROVEN 81-97us session band); R9/R10:
// deeper pipelining costs registers/occupancy — keep body register-lean.
// Plain __launch_bounds__(256): hints spill (R3/R4). Keep K/V staging (R1/R5).
__global__ __launch_bounds__(256) void attn_mfma(const u16* __restrict__ qkvb,
                                                 const u16* __restrict__ Kp,
                                                 const u16* __restrict__ Vp,
                                                 const u16* __restrict__ EKP,
                                                 const u16* __restrict__ EVP,
                                                 u16* __restrict__ yb,
                                                 float* __restrict__ po,
                                                 float* __restrict__ lsp) {
    __shared__ __align__(16) u16 slab_[4][2560];   // 20480 B, per-wave overlay
    __shared__ __align__(16) u16 KVs[16384];       // 32768 B: K [0..8192), V [8192..)

    const int tid = threadIdx.x;
    const int w = tid >> 6, L = tid & 63;
    const int l15 = L & 15, quad = L >> 4;
    const int bid = blockIdx.x;                    // [0, 1152)
    const int xcd = bid & 7, slot = bid >> 3;
    const int bh = (slot / 18) * 8 + xcd;
    const int blk = slot % 18;
    const int b = bh >> 4, h = bh & 15;
    u16* S2l = slab_[w];
    u16* Pl  = slab_[w];
    u16* Ppl = slab_[w];

    const bf8* EKPF = (const bf8*)EKP;
    const bf8* EVPF = (const bf8*)EVP;

    bf8 qn[2];
    f32x4 o[4];
    float lsum[4];
    int t = -1, t0 = 0;

    auto flush = [&](int tt) {
        float lr[4];
        #pragma unroll
        for (int r = 0; r < 4; ++r) {
            float s = lsum[r];
            s += __shfl_xor(s, 1); s += __shfl_xor(s, 2);
            s += __shfl_xor(s, 4); s += __shfl_xor(s, 8);
            lr[r] = s;
        }
        const bool whole = (d_S[tt] >> 2) == ((d_S[tt + 1] - 1) >> 2);
        if (whole) {           // all units of this tile in this block: finalize
            #pragma unroll
            for (int tn = 0; tn < 4; ++tn) {
                const int col = h * 64 + tn * 16 + l15;
                #pragma unroll
                for (int r = 0; r < 4; ++r) {
                    const int trow = tt * 64 + w * 16 + quad * 4 + r;
                    yb[(size_t)(b * 1024 + trow) * 1024 + col] = f2b(o[tn][r] / lr[r]);
                }
            }
        } else {               // partial: statically-indexed slot
            const int slot2 = blk - (d_S[tt] >> 2);
            const size_t sidx = (size_t)(bh * 19 + d_SB[tt] + slot2);
            float* pob = po + (sidx << 12);
            #pragma unroll
            for (int tn = 0; tn < 4; ++tn)
                #pragma unroll
                for (int r = 0; r < 4; ++r)
                    pob[(w * 16 + quad * 4 + r) * 64 + tn * 16 + l15] = o[tn][r];
            if (l15 == 0) {
                float* lsb = lsp + (sidx << 6);
                #pragma unroll
                for (int r = 0; r < 4; ++r) lsb[w * 16 + quad * 4 + r] = lr[r];
            }
        }
    };

    #pragma unroll 1
    for (int ui = 0; ui < 4; ++ui) {
        const int u = blk * 4 + ui;
        int nt = (t < 0) ? 0 : t;
        while (d_S[nt + 1] <= u) ++nt;
        if (nt != t) {
            if (t >= 0) flush(t);
            t = nt; t0 = t * 64;
            const int trow = t0 + w * 16 + l15;
            const u16* qp = qkvb + (size_t)(b * 1024 + trow) * 3072 + h * 64 + quad * 8;
            qn[0] = *(const bf8*)qp;
            qn[1] = *(const bf8*)(qp + 32);
            #pragma unroll
            for (int tn = 0; tn < 4; ++tn)
                #pragma unroll
                for (int j = 0; j < 4; ++j) o[tn][j] = 0.f;
            #pragma unroll
            for (int r = 0; r < 4; ++r) lsum[r] = 0.f;
        }
        const int c = u - d_S[t];
        const int s0 = c << 7;
        const int diff = t0 - s0;                 // >= 0, multiple of 64

        __syncthreads();    // bar1: prior unit's LDS reads retired (drain ~free)

        // ---- issue K DMA only (16 KB contiguous) ----
        {
            const size_t kbase = ((size_t)(bh * 64 + (s0 >> 4)) << 1) * 512;
            #pragma unroll
            for (int i = 0; i < 4; ++i)
                async16(Kp + kbase + (i * 256 + tid) * 8, &KVs[(i * 256 + tid) * 8]);
        }

        // ---- S2 = Q @ EK^T (global EKP stream; covers K DMA latency) ----
        f32x4 s2[9] = {};
        {
            const int kb = (diff >> 4) + w;       // k16 base
            #pragma unroll
            for (int j = 0; j < 9; ++j) {
                #pragma unroll
                for (int kc = 0; kc < 2; ++kc)
                    s2[j] = __builtin_amdgcn_mfma_f32_16x16x32_bf16(
                        qn[kc], EKPF[(((kb + j) << 1) + kc) * 64 + L], s2[j], 0, 0, 0);
            }
        }
        #pragma unroll
        for (int j = 0; j < 9; ++j)
            #pragma unroll
            for (int r = 0; r < 4; ++r)
                S2l[(quad * 4 + r) * 148 + j * 16 + l15] = f2b(s2[j][r]);

        // ---- issue V DMA LAST (latency hides under S1 + softmax + scatter) ----
        __builtin_amdgcn_sched_barrier(0);   // pin V issue after all S2 loads
        {
            const int vb = bh * 128 + (s0 >> 5);
            #pragma unroll
            for (int i = 0; i < 4; ++i)
                async16(Vp + ((size_t)(vb + i * 32) * 512 + tid * 8),
                        &KVs[8192 + i * 2048 + tid * 8]);
        }

        // ---- wait K only (4 oldest VMEM; V stays in flight), rendezvous ----
        asm volatile("s_waitcnt vmcnt(4)" ::: "memory");
        __builtin_amdgcn_s_barrier();
        __builtin_amdgcn_sched_barrier(0);

        // ---- S1 = Q @ (K/8)^T from LDS ----
        f32x4 s1[8];
        __builtin_amdgcn_s_setprio(1);
        #pragma unroll
        for (int tn = 0; tn < 8; ++tn) {
            f32x4 z = {};
            #pragma unroll
            for (int kc = 0; kc < 2; ++kc) {
                const bf8 kf = *(const bf8*)&KVs[((tn << 1) + kc) * 512 + L * 8];
                z = __builtin_amdgcn_mfma_f32_16x16x32_bf16(qn[kc], kf, z, 0, 0, 0);
            }
            s1[tn] = z;
        }
        __builtin_amdgcn_s_setprio(0);

        // ---- logits + mask + p = exp(logit - 4); per-lane partial sums ----
        #pragma unroll
        for (int tn = 0; tn < 8; ++tn) {
            const int cl = tn * 16 + l15;
            #pragma unroll
            for (int r = 0; r < 4; ++r) {
                const int row = quad * 4 + r;
                float v = s1[tn][r] + b2f(S2l[row * 148 + (row - cl + 127)]);
                if (cl > diff + w * 16 + row) v = -1e30f;
                float p = __expf(v - 4.0f);       // masked -> 0
                s1[tn][r] = p;
                lsum[r] += p;
            }
        }

        // ---- scatter P in MFMA A-layout (clobbers dead S2l region) ----
        #pragma unroll
        for (int tn = 0; tn < 8; ++tn) {
            const int cl = tn * 16 + l15;
            #pragma unroll
            for (int r = 0; r < 4; ++r) {
                const int row = quad * 4 + r;
                Pl[((cl >> 5) << 9) + (((cl >> 3) & 3) << 7) + (row << 3) + (cl & 7)]
                    = f2b(s1[tn][r]);
            }
        }
        // ---- read P fragments (in-order DS: reads precede overlay writes) ----
        bf8 pa[4];
        #pragma unroll
        for (int kc = 0; kc < 4; ++kc) pa[kc] = ((const bf8*)Pl)[kc * 64 + L];

        // ---- rebuild overlay as sheared P' (zero pads, then scatter) ----
        #pragma unroll
        for (int i = 0; i < 5; ++i)
            ((uint4*)Ppl)[i * 64 + L] = make_uint4(0, 0, 0, 0);
        #pragma unroll
        for (int tn = 0; tn < 8; ++tn) {
            const int cl = tn * 16 + l15;
            #pragma unroll
            for (int r = 0; r < 4; ++r) {
                const int row = quad * 4 + r;
                const int dc = (w & 1) * 16 + row - cl + 127;   // [0,158]
                Ppl[((dc >> 5) << 9) + (((dc >> 3) & 3) << 7) + (row << 3) + (dc & 7)]
                    = f2b(s1[tn][r]);
            }
        }

        __syncthreads();    // bar3: V visible to all waves (drain ~free, V landed)
        __builtin_amdgcn_sched_barrier(0);

        // ---- O += P @ V (V frags from LDS) ----
        __builtin_amdgcn_s_setprio(1);
        {
            #pragma unroll
            for (int tn = 0; tn < 4; ++tn) {
                #pragma unroll
                for (int kc = 0; kc < 4; ++kc) {
                    const bf8 vf = *(const bf8*)&KVs[8192 + (tn * 4 + kc) * 512 + L * 8];
                    o[tn] = __builtin_amdgcn_mfma_f32_16x16x32_bf16(
                        pa[kc], vf, o[tn], 0, 0, 0);
                }
            }
        }
        // ---- O += P' @ EV (global EVP stream) ----
        {
            bf8 pb[5];
            #pragma unroll
            for (int kc = 0; kc < 5; ++kc) pb[kc] = ((const bf8*)Ppl)[kc * 64 + L];
            const int eb = (diff >> 5) + (w >> 1);
            #pragma unroll
            for (int tn = 0; tn < 4; ++tn) {
                #pragma unroll
                for (int kc = 0; kc < 5; ++kc)
                    o[tn] = __builtin_amdgcn_mfma_f32_16x16x32_bf16(
                        pb[kc], EVPF[(tn * 36 + eb + kc) * 64 + L], o[tn], 0, 0, 0);
            }
        }
        __builtin_amdgcn_s_setprio(0);
    }
    flush(t);
}

// ---------------- combine partial (o, lsum) slots for split tiles, normalize -------
__global__ __launch_bounds__(256) void attn_reduce(const float* __restrict__ po,
                                                   const float* __restrict__ lsp,
                                                   u16* __restrict__ yb) {
    const int gi = blockIdx.x;                    // 0 -> tile 4, i -> tile i+7
    const int t = (gi == 0) ? 4 : (gi + 7);
    const int bh = blockIdx.y, b = bh >> 4, h = bh & 15;
    const int ns = (t == 12) ? 3 : 2;
    const size_t base = (size_t)(bh * 19 + d_SB[t]);
    const float* pob = po + (base << 12);
    const float* lsb = lsp + (base << 6);
    #pragma unroll 1
    for (int i = 0; i < 16; ++i) {
        const int idx = i * 256 + threadIdx.x;
        const int row = idx >> 6, col = idx & 63;
        float acc = 0.f, lacc = 0.f;
        for (int s = 0; s < ns; ++s) {
            acc  += pob[(s << 12) + idx];
            lacc += lsb[(s << 6) + row];
        }
        yb[(size_t)(b * 1024 + t * 64 + row) * 1024 + h * 64 + col] = f2b(acc / lacc);
    }
}

extern "C" void kernel_launch(void* const* d_in, const int* in_sizes, int n_in,
                              void* d_out, int out_size, void* d_ws, size_t ws_size,
                              hipStream_t stream) {
    const float* x      = (const float*)d_in[0];
    const float* w_attn = (const float*)d_in[1];
    const float* w_proj = (const float*)d_in[2];
    const float* embk   = (const float*)d_in[3];
    const float* embv   = (const float*)d_in[4];
    float* out = (float*)d_out;

    u16* wsb   = (u16*)d_ws;
    u16* qkvb  = wsb;                  // 4096*3072 (only Q cols live now)
    u16* xb    = qkvb + 12582912;      // 4096*1024            = 4194304
    u16* ymidb = xb;                   // aliases xb (xb dead after gemm1)
    u16* waT   = xb + 4194304;         // 3072*1024            = 3145728
    u16* wpT   = waT + 3145728;        // 1024*1024            = 1048576
    u16* Vt    = wpT + 1048576;        // (slot unused; layout kept stable)
    u16* Kp    = Vt + 4194304;         // 64*64*2*512          = 4194304
    u16* Vp    = Kp + 4194304;         // 64*4*32*512          = 4194304
    u16* EKP   = Vp + 4194304;         // 72*2*512             = 73728
    u16* EVP   = EKP + 73728;          // 4*36*512             = 73728
    float* po  = (float*)(EVP + 73728);// 64*19*4096 f32       = 4980736 f32
    float* lsp = po + 4980736;         // 64*19*64 f32         = 77824 f32

    prep_all<<<dim3(5192), 256, 0, stream>>>(x, embk, embv, w_attn, w_proj,
                                             xb, EKP, EVP, waT, wpT);
    gemm_mfma<u16><<<dim3(24, 32), 256, 0, stream>>>(xb, waT, qkvb, Kp, Vp,
                                                     4096, 3072, 1024);
    attn_mfma<<<dim3(1152), 256, 0, stream>>>(qkvb, Kp, Vp, EKP, EVP, ymidb, po, lsp);
    attn_reduce<<<dim3(9, 64), 256, 0, stream>>>(po, lsp, ymidb);
    gemm_mfma64<float><<<dim3(8, 64), 256, 0, stream>>>(ymidb, wpT, out, 4096, 1024, 1024);
}

// Round 19
// 230.473 us; speedup vs baseline: 1.0265x; 1.0107x over previous
//
#include <hip/hip_runtime.h>
#include <math.h>

typedef unsigned short u16;
typedef short bf8 __attribute__((ext_vector_type(8)));      // 8 bf16 (raw bits)
typedef float f32x4 __attribute__((ext_vector_type(4)));

__device__ __forceinline__ u16 f2b(float f) {
    union { float f; unsigned u; } x; x.f = f;
    return (u16)((x.u + 0x7FFFu + ((x.u >> 16) & 1u)) >> 16);   // RTNE
}
__device__ __forceinline__ float b2f(u16 b) {
    union { unsigned u; float f; } x; x.u = ((unsigned)b) << 16;
    return x.f;
}

__device__ __forceinline__ void async16(const void* g, void* l) {
    __builtin_amdgcn_global_load_lds(
        (const __attribute__((address_space(1))) unsigned int*)g,
        (__attribute__((address_space(3))) unsigned int*)l, 16, 0, 0);
}

__device__ __forceinline__ void cstore(float* p, float v) { *p = v; }
__device__ __forceinline__ void cstore(u16* p, float v) { *p = f2b(v); }

// ---------------- bf16 MFMA GEMM (m97 structure): C[M,N] = A[M,K] @ Bt[N,K]^T ------
// BK=32 (R12: BK=64 regressed). R14 K-FUSION + R15 V-FUSION (bit-identical,
// pack kernels deleted). R19: XCD-AWARE SWIZZLE (T1, mirrors R18's attn win:
// FETCH 65->13.6MB). 1D grid 768; each XCD owns a 12(bx) x 8(by) rectangle:
//   xcd = bid&7, s = bid>>3, bx = (xcd&1)*12 + s%12, by = (xcd>>1)*8 + s/12.
// Bijective (24=2x12, 32=4x8). Per-XCD working set: 12 B-panels (3MB) +
// 8 A-panels (2MB) = 5MB ~ L2 (was ~14MB round-robined). Panel re-reads
// (A-panel x24, B-panel x32) become XCD-local. Pure index permutation (G16).
template<typename OutT>
__global__ __launch_bounds__(256) void gemm_mfma(const u16* __restrict__ A,
                                                 const u16* __restrict__ Bt,
                                                 OutT* __restrict__ C,
                                                 u16* __restrict__ KP,
                                                 u16* __restrict__ VP,
                                                 int M, int N, int K) {
    __shared__ __align__(16) u16 sh[128 * 128];    // K-loop: As=[0,4096) Bs=[4096,8192); epilogue: ts[128][128]
    u16* As = sh;
    u16* Bs = sh + 128 * 32;
    const int tid = threadIdx.x;
    const int w = tid >> 6, L = tid & 63;
    const int l15 = L & 15, quad = L >> 4;
    const int wm = (w >> 1) * 64, wn = (w & 1) * 64;
    const int bid = blockIdx.x;                    // [0, 768)
    const int xcd = bid & 7, sblk = bid >> 3;
    const int bx = (xcd & 1) * 12 + (sblk % 12);
    const int by = (xcd >> 1) * 8 + (sblk / 12);
    const int row0 = by * 128, col0 = bx * 128;
    const int laneRow = L >> 2, laneCol8 = (L & 3) * 8;

    f32x4 acc[4][4] = {};

    for (int k0 = 0; k0 < K; k0 += 32) {
        #pragma unroll
        for (int i = 0; i < 2; ++i) {
            const int seg = w * 2 + i;
            const int r = seg * 16 + laneRow;
            async16(&A[(size_t)(row0 + r) * K + k0 + laneCol8], &As[seg * 512 + L * 8]);
        }
        #pragma unroll
        for (int i = 0; i < 2; ++i) {
            const int seg = w * 2 + i;
            const int r = seg * 16 + laneRow;
            async16(&Bt[(size_t)(col0 + r) * K + k0 + laneCol8], &Bs[seg * 512 + L * 8]);
        }
        __syncthreads();
        bf8 a[4], b[4];
        #pragma unroll
        for (int mt = 0; mt < 4; ++mt)
            a[mt] = *(const bf8*)&As[(wm + mt * 16 + l15) * 32 + quad * 8];
        #pragma unroll
        for (int nt = 0; nt < 4; ++nt)
            b[nt] = *(const bf8*)&Bs[(wn + nt * 16 + l15) * 32 + quad * 8];
        #pragma unroll
        for (int mt = 0; mt < 4; ++mt)
            #pragma unroll
            for (int nt = 0; nt < 4; ++nt)
                acc[mt][nt] = __builtin_amdgcn_mfma_f32_16x16x32_bf16(
                    a[mt], b[nt], acc[mt][nt], 0, 0, 0);
        __syncthreads();
    }
    if (VP != nullptr && col0 >= 2048) {
        // V-block: transpose through LDS, emit Vp fragments (pack_v fused here)
        u16* ts = sh;                              // [s_local][hl*64 + d], 128x128
        #pragma unroll
        for (int mt = 0; mt < 4; ++mt)
            #pragma unroll
            for (int nt = 0; nt < 4; ++nt) {
                const int cloc = wn + nt * 16 + l15;
                #pragma unroll
                for (int r = 0; r < 4; ++r) {
                    const int rloc = wm + mt * 16 + quad * 4 + r;
                    ts[rloc * 128 + cloc] = f2b(acc[mt][nt][r]);
                }
            }
        __syncthreads();
        const int b = row0 >> 10;
        const int h0 = (col0 - 2048) >> 6;
        const int c32base = (row0 >> 5) & 31;
        #pragma unroll
        for (int j = 0; j < 8; ++j) {
            const int f = j * 256 + tid;           // frag id in [0, 2048)
            const int hl = f >> 10, tn2 = (f >> 8) & 3, c32l = (f >> 6) & 3;
            const int Lf = f & 63, l15f = f & 15, quadf = (f >> 4) & 3;
            __align__(16) u16 buf[8];
            #pragma unroll
            for (int i = 0; i < 8; ++i)
                buf[i] = ts[(c32l * 32 + quadf * 8 + i) * 128 + hl * 64 + tn2 * 16 + l15f];
            const int bh = (b << 4) + h0 + hl;
            *(uint4*)(VP + ((size_t)(bh * 8192 + tn2 * 2048 + (c32base + c32l) * 64 + Lf) << 3))
                = *(uint4*)buf;
        }
    } else if (KP != nullptr && col0 >= 1024) {
        // K-block: emit fragment-linear Kp (pre-scaled by 1/8)
        #pragma unroll
        for (int mt = 0; mt < 4; ++mt)
            #pragma unroll
            for (int nt = 0; nt < 4; ++nt) {
                const int hd = col0 - 1024 + wn + nt * 16 + l15;
                const int h = hd >> 6, d = hd & 63;
                const int doff = ((d >> 5) << 6) + (((d >> 3) & 3) << 4);
                #pragma unroll
                for (int r = 0; r < 4; ++r) {
                    const int row = row0 + wm + mt * 16 + quad * 4 + r;
                    const int b = row >> 10, s = row & 1023;
                    const size_t idx =
                        ((size_t)((((b << 4) + h) << 13) + ((s >> 4) << 7) + doff + (s & 15)) << 3)
                        + (d & 7);
                    KP[idx] = f2b(acc[mt][nt][r] * 0.125f);
                }
            }
    } else {
        #pragma unroll
        for (int mt = 0; mt < 4; ++mt)
            #pragma unroll
            for (int nt = 0; nt < 4; ++nt) {
                const int col = col0 + wn + nt * 16 + l15;
                #pragma unroll
                for (int r = 0; r < 4; ++r) {
                    const int row = row0 + wm + mt * 16 + quad * 4 + r;
                    cstore(&C[(size_t)row * N + col], acc[mt][nt][r]);
                }
            }
    }
}

// ---------------- 64x128-tile variant (gemm2): 2 blocks/CU — the optimum ----------
// Bracketed: 128x128 @1 blk/CU slow, 64x128 @2 blk/CU best (R7/R15),
// 64x64 @4 blk/CU worse (R16). BK=32 (R12).
template<typename OutT>
__global__ __launch_bounds__(256) void gemm_mfma64(const u16* __restrict__ A,
                                                   const u16* __restrict__ Bt,
                                                   OutT* __restrict__ C,
                                                   int M, int N, int K) {
    __shared__ __align__(16) u16 As[64 * 32];
    __shared__ __align__(16) u16 Bs[128 * 32];
    const int tid = threadIdx.x;
    const int w = tid >> 6, L = tid & 63;
    const int l15 = L & 15, quad = L >> 4;
    const int wm = (w >> 1) * 32, wn = (w & 1) * 64;
    const int row0 = blockIdx.y * 64, col0 = blockIdx.x * 128;
    const int laneRow = L >> 2, laneCol8 = (L & 3) * 8;

    f32x4 acc[2][4] = {};

    for (int k0 = 0; k0 < K; k0 += 32) {
        {   // A: 64x32 = 256 chunks, one per thread (seg = w)
            const int r = w * 16 + laneRow;
            async16(&A[(size_t)(row0 + r) * K + k0 + laneCol8], &As[w * 512 + L * 8]);
        }
        #pragma unroll
        for (int i = 0; i < 2; ++i) {   // B: 128x32 = 512 chunks, two per thread
            const int seg = w * 2 + i;
            const int r = seg * 16 + laneRow;
            async16(&Bt[(size_t)(col0 + r) * K + k0 + laneCol8], &Bs[seg * 512 + L * 8]);
        }
        __syncthreads();
        bf8 a[2], b[4];
        #pragma unroll
        for (int mt = 0; mt < 2; ++mt)
            a[mt] = *(const bf8*)&As[(wm + mt * 16 + l15) * 32 + quad * 8];
        #pragma unroll
        for (int nt = 0; nt < 4; ++nt)
            b[nt] = *(const bf8*)&Bs[(wn + nt * 16 + l15) * 32 + quad * 8];
        #pragma unroll
        for (int mt = 0; mt < 2; ++mt)
            #pragma unroll
            for (int nt = 0; nt < 4; ++nt)
                acc[mt][nt] = __builtin_amdgcn_mfma_f32_16x16x32_bf16(
                    a[mt], b[nt], acc[mt][nt], 0, 0, 0);
        __syncthreads();
    }
    #pragma unroll
    for (int mt = 0; mt < 2; ++mt)
        #pragma unroll
        for (int nt = 0; nt < 4; ++nt) {
            const int col = col0 + wn + nt * 16 + l15;
            #pragma unroll
            for (int r = 0; r < 4; ++r) {
                const int row = row0 + wm + mt * 16 + quad * 4 + r;
                cstore(&C[(size_t)row * N + col], acc[mt][nt][r]);
            }
        }
}

// ---------------- merged prep: x->bf16, EKP/EVP fragment tables, weight transposes --
__global__ __launch_bounds__(256) void prep_all(const float* __restrict__ x,
                                                const float* __restrict__ embk,
                                                const float* __restrict__ embv,
                                                const float* __restrict__ w_attn,
                                                const float* __restrict__ w_proj,
                                                u16* __restrict__ xb,
                                                u16* __restrict__ EKP,
                                                u16* __restrict__ EVP,
                                                u16* __restrict__ waT,
                                                u16* __restrict__ wpT) {
    __shared__ u16 ts[64][65];
    const int bx = blockIdx.x;
    const int tid = threadIdx.x;
    if (bx < 4096) {
        int idx = bx * 256 + tid;
        const float4 v = ((const float4*)x)[idx];
        ((ushort4*)xb)[idx] = make_ushort4(f2b(v.x), f2b(v.y), f2b(v.z), f2b(v.w));
    } else if (bx < 4132) {
        int t = (bx - 4096) * 256 + tid;           // [0, 9216)
        int L = t & 63, kc = (t >> 6) & 1, k16 = t >> 7;
        int l15 = L & 15, quad = L >> 4;
        int row = 1 + k16 * 16 + l15;
        int d = row - 128;
        int cl = d < 0 ? 0 : (d > 1023 ? 1023 : d);
        const float* p = embk + cl * 64 + kc * 32 + quad * 8;
        #pragma unroll
        for (int i = 0; i < 8; ++i) EKP[t * 8 + i] = f2b(p[i]);
    } else if (bx < 4168) {
        int t = (bx - 4132) * 256 + tid;           // [0, 9216)
        int L = t & 63, rest = t >> 6;             // rest = tn*36 + c32
        int c32 = rest % 36, tn = rest / 36;
        int l15 = L & 15, quad = L >> 4;
        #pragma unroll
        for (int i = 0; i < 8; ++i) {
            int c = c32 * 32 + quad * 8 + i;
            int d = c - 127;
            int cl = d < 0 ? 0 : (d > 1023 ? 1023 : d);
            EVP[t * 8 + i] = f2b(embv[cl * 64 + tn * 16 + l15]);
        }
    } else {
        const float* W; u16* WT; int Cc, t;
        if (bx < 4168 + 768) { t = bx - 4168; W = w_attn; WT = waT; Cc = 3072; }
        else                 { t = bx - 4936; W = w_proj; WT = wpT; Cc = 1024; }
        const int nx = Cc >> 6;
        const int c0 = (t % nx) * 64, r0 = (t / nx) * 64;
        for (int i = tid; i < 4096; i += 256) {
            int r = i >> 6, c = i & 63;
            ts[r][c] = f2b(W[(size_t)(r0 + r) * Cc + c0 + c]);
        }
        __syncthreads();
        for (int i = tid; i < 4096; i += 256) {
            int c = i >> 6, r = i & 63;
            WT[(size_t)(c0 + c) * 1024 + r0 + r] = ts[r][c];
        }
    }
}

// cumulative chunk counts: tile t owns units [S(t), S(t)+t/2+1); S(16)=72 total.
__device__ const int d_S[17] = {0,1,2,4,6,9,12,16,20,25,30,36,42,49,56,64,72};
// partial-slot base per split tile (tiles 4, 8..15), compact: 19 slots per bh.
// tile:       0  1  2  3  4  5  6  7  8  9 10 11 12 13 14 15
__device__ const int d_SB[16] = {0,0,0,0, 0,0,0,0, 2, 4, 6, 8,10,13,15,17};

// ---------------- MFMA fused attention with RPE: split-barrier staged pipeline -----
// R18 XCD SWIZZLE (WIN: FETCH 65->13.6MB, attn -2us): 1D grid 1152;
//   xcd = bid&7, slot = bid>>3, bh = (slot/18)*8 + xcd, blk = slot%18.
// All 18 blocks sharing one bh's Kp/Vp/EKP land on ONE XCD's L2.
// R8 schedule otherwise (PROVEN): bar1 -> K DMA -> S2 covers K -> V DMA LAST
// -> vmcnt(4) (V in flight) -> s_barrier -> S1 -> softmax+scatter (covers V)
// -> bar3 -> PV + P'EV. setprio(1) on MFMA clusters.
// R9/R10: deeper pipelining costs registers/occupancy — keep body lean.
// Plain __launch_bounds__(256): hints spill (R3/R4). Keep K/V staging (R1/R5).
__global__ __launch_bounds__(256) void attn_mfma(const u16* __restrict__ qkvb,
                                                 const u16* __restrict__ Kp,
                                                 const u16* __restrict__ Vp,
                                                 const u16* __restrict__ EKP,
                                                 const u16* __restrict__ EVP,
                                                 u16* __restrict__ yb,
                                                 float* __restrict__ po,
                                                 float* __restrict__ lsp) {
    __shared__ __align__(16) u16 slab_[4][2560];   // 20480 B, per-wave overlay
    __shared__ __align__(16) u16 KVs[16384];       // 32768 B: K [0..8192), V [8192..)

    const int tid = threadIdx.x;
    const int w = tid >> 6, L = tid & 63;
    const int l15 = L & 15, quad = L >> 4;
    const int bid = blockIdx.x;                    // [0, 1152)
    const int xcd = bid & 7, slot = bid >> 3;
    const int bh = (slot / 18) * 8 + xcd;
    const int blk = slot % 18;
    const int b = bh >> 4, h = bh & 15;
    u16* S2l = slab_[w];
    u16* Pl  = slab_[w];
    u16* Ppl = slab_[w];

    const bf8* EKPF = (const bf8*)EKP;
    const bf8* EVPF = (const bf8*)EVP;

    bf8 qn[2];
    f32x4 o[4];
    float lsum[4];
    int t = -1, t0 = 0;

    auto flush = [&](int tt) {
        float lr[4];
        #pragma unroll
        for (int r = 0; r < 4; ++r) {
            float s = lsum[r];
            s += __shfl_xor(s, 1); s += __shfl_xor(s, 2);
            s += __shfl_xor(s, 4); s += __shfl_xor(s, 8);
            lr[r] = s;
        }
        const bool whole = (d_S[tt] >> 2) == ((d_S[tt + 1] - 1) >> 2);
        if (whole) {           // all units of this tile in this block: finalize
            #pragma unroll
            for (int tn = 0; tn < 4; ++tn) {
                const int col = h * 64 + tn * 16 + l15;
                #pragma unroll
                for (int r = 0; r < 4; ++r) {
                    const int trow = tt * 64 + w * 16 + quad * 4 + r;
                    yb[(size_t)(b * 1024 + trow) * 1024 + col] = f2b(o[tn][r] / lr[r]);
                }
            }
        } else {               // partial: statically-indexed slot
            const int slot2 = blk - (d_S[tt] >> 2);
            const size_t sidx = (size_t)(bh * 19 + d_SB[tt] + slot2);
            float* pob = po + (sidx << 12);
            #pragma unroll
            for (int tn = 0; tn < 4; ++tn)
                #pragma unroll
                for (int r = 0; r < 4; ++r)
                    pob[(w * 16 + quad * 4 + r) * 64 + tn * 16 + l15] = o[tn][r];
            if (l15 == 0) {
                float* lsb = lsp + (sidx << 6);
                #pragma unroll
                for (int r = 0; r < 4; ++r) lsb[w * 16 + quad * 4 + r] = lr[r];
            }
        }
    };

    #pragma unroll 1
    for (int ui = 0; ui < 4; ++ui) {
        const int u = blk * 4 + ui;
        int nt = (t < 0) ? 0 : t;
        while (d_S[nt + 1] <= u) ++nt;
        if (nt != t) {
            if (t >= 0) flush(t);
            t = nt; t0 = t * 64;
            const int trow = t0 + w * 16 + l15;
            const u16* qp = qkvb + (size_t)(b * 1024 + trow) * 3072 + h * 64 + quad * 8;
            qn[0] = *(const bf8*)qp;
            qn[1] = *(const bf8*)(qp + 32);
            #pragma unroll
            for (int tn = 0; tn < 4; ++tn)
                #pragma unroll
                for (int j = 0; j < 4; ++j) o[tn][j] = 0.f;
            #pragma unroll
            for (int r = 0; r < 4; ++r) lsum[r] = 0.f;
        }
        const int c = u - d_S[t];
        const int s0 = c << 7;
        const int diff = t0 - s0;                 // >= 0, multiple of 64

        __syncthreads();    // bar1: prior unit's LDS reads retired (drain ~free)

        // ---- issue K DMA only (16 KB contiguous) ----
        {
            const size_t kbase = ((size_t)(bh * 64 + (s0 >> 4)) << 1) * 512;
            #pragma unroll
            for (int i = 0; i < 4; ++i)
                async16(Kp + kbase + (i * 256 + tid) * 8, &KVs[(i * 256 + tid) * 8]);
        }

        // ---- S2 = Q @ EK^T (global EKP stream; covers K DMA latency) ----
        f32x4 s2[9] = {};
        {
            const int kb = (diff >> 4) + w;       // k16 base
            #pragma unroll
            for (int j = 0; j < 9; ++j) {
                #pragma unroll
                for (int kc = 0; kc < 2; ++kc)
                    s2[j] = __builtin_amdgcn_mfma_f32_16x16x32_bf16(
                        qn[kc], EKPF[(((kb + j) << 1) + kc) * 64 + L], s2[j], 0, 0, 0);
            }
        }
        #pragma unroll
        for (int j = 0; j < 9; ++j)
            #pragma unroll
            for (int r = 0; r < 4; ++r)
                S2l[(quad * 4 + r) * 148 + j * 16 + l15] = f2b(s2[j][r]);

        // ---- issue V DMA LAST (latency hides under S1 + softmax + scatter) ----
        __builtin_amdgcn_sched_barrier(0);   // pin V issue after all S2 loads
        {
            const int vb = bh * 128 + (s0 >> 5);
            #pragma unroll
            for (int i = 0; i < 4; ++i)
                async16(Vp + ((size_t)(vb + i * 32) * 512 + tid * 8),
                        &KVs[8192 + i * 2048 + tid * 8]);
        }

        // ---- wait K only (4 oldest VMEM; V stays in flight), rendezvous ----
        asm volatile("s_waitcnt vmcnt(4)" ::: "memory");
        __builtin_amdgcn_s_barrier();
        __builtin_amdgcn_sched_barrier(0);

        // ---- S1 = Q @ (K/8)^T from LDS ----
        f32x4 s1[8];
        __builtin_amdgcn_s_setprio(1);
        #pragma unroll
        for (int tn = 0; tn < 8; ++tn) {
            f32x4 z = {};
            #pragma unroll
            for (int kc = 0; kc < 2; ++kc) {
                const bf8 kf = *(const bf8*)&KVs[((tn << 1) + kc) * 512 + L * 8];
                z = __builtin_amdgcn_mfma_f32_16x16x32_bf16(qn[kc], kf, z, 0, 0, 0);
            }
            s1[tn] = z;
        }
        __builtin_amdgcn_s_setprio(0);

        // ---- logits + mask + p = exp(logit - 4); per-lane partial sums ----
        #pragma unroll
        for (int tn = 0; tn < 8; ++tn) {
            const int cl = tn * 16 + l15;
            #pragma unroll
            for (int r = 0; r < 4; ++r) {
                const int row = quad * 4 + r;
                float v = s1[tn][r] + b2f(S2l[row * 148 + (row - cl + 127)]);
                if (cl > diff + w * 16 + row) v = -1e30f;
                float p = __expf(v - 4.0f);       // masked -> 0
                s1[tn][r] = p;
                lsum[r] += p;
            }
        }

        // ---- scatter P in MFMA A-layout (clobbers dead S2l region) ----
        #pragma unroll
        for (int tn = 0; tn < 8; ++tn) {
            const int cl = tn * 16 + l15;
            #pragma unroll
            for (int r = 0; r < 4; ++r) {
                const int row = quad * 4 + r;
                Pl[((cl >> 5) << 9) + (((cl >> 3) & 3) << 7) + (row << 3) + (cl & 7)]
                    = f2b(s1[tn][r]);
            }
        }
        // ---- read P fragments (in-order DS: reads precede overlay writes) ----
        bf8 pa[4];
        #pragma unroll
        for (int kc = 0; kc < 4; ++kc) pa[kc] = ((const bf8*)Pl)[kc * 64 + L];

        // ---- rebuild overlay as sheared P' (zero pads, then scatter) ----
        #pragma unroll
        for (int i = 0; i < 5; ++i)
            ((uint4*)Ppl)[i * 64 + L] = make_uint4(0, 0, 0, 0);
        #pragma unroll
        for (int tn = 0; tn < 8; ++tn) {
            const int cl = tn * 16 + l15;
            #pragma unroll
            for (int r = 0; r < 4; ++r) {
                const int row = quad * 4 + r;
                const int dc = (w & 1) * 16 + row - cl + 127;   // [0,158]
                Ppl[((dc >> 5) << 9) + (((dc >> 3) & 3) << 7) + (row << 3) + (dc & 7)]
                    = f2b(s1[tn][r]);
            }
        }

        __syncthreads();    // bar3: V visible to all waves (drain ~free, V landed)
        __builtin_amdgcn_sched_barrier(0);

        // ---- O += P @ V (V frags from LDS) ----
        __builtin_amdgcn_s_setprio(1);
        {
            #pragma unroll
            for (int tn = 0; tn < 4; ++tn) {
                #pragma unroll
                for (int kc = 0; kc < 4; ++kc) {
                    const bf8 vf = *(const bf8*)&KVs[8192 + (tn * 4 + kc) * 512 + L * 8];
                    o[tn] = __builtin_amdgcn_mfma_f32_16x16x32_bf16(
                        pa[kc], vf, o[tn], 0, 0, 0);
                }
            }
        }
        // ---- O += P' @ EV (global EVP stream) ----
        {
            bf8 pb[5];
            #pragma unroll
            for (int kc = 0; kc < 5; ++kc) pb[kc] = ((const bf8*)Ppl)[kc * 64 + L];
            const int eb = (diff >> 5) + (w >> 1);
            #pragma unroll
            for (int tn = 0; tn < 4; ++tn) {
                #pragma unroll
                for (int kc = 0; kc < 5; ++kc)
                    o[tn] = __builtin_amdgcn_mfma_f32_16x16x32_bf16(
                        pb[kc], EVPF[(tn * 36 + eb + kc) * 64 + L], o[tn], 0, 0, 0);
            }
        }
        __builtin_amdgcn_s_setprio(0);
    }
    flush(t);
}

// ---------------- combine partial (o, lsum) slots for split tiles, normalize -------
__global__ __launch_bounds__(256) void attn_reduce(const float* __restrict__ po,
                                                   const float* __restrict__ lsp,
                                                   u16* __restrict__ yb) {
    const int gi = blockIdx.x;                    // 0 -> tile 4, i -> tile i+7
    const int t = (gi == 0) ? 4 : (gi + 7);
    const int bh = blockIdx.y, b = bh >> 4, h = bh & 15;
    const int ns = (t == 12) ? 3 : 2;
    const size_t base = (size_t)(bh * 19 + d_SB[t]);
    const float* pob = po + (base << 12);
    const float* lsb = lsp + (base << 6);
    #pragma unroll 1
    for (int i = 0; i < 16; ++i) {
        const int idx = i * 256 + threadIdx.x;
        const int row = idx >> 6, col = idx & 63;
        float acc = 0.f, lacc = 0.f;
        for (int s = 0; s < ns; ++s) {
            acc  += pob[(s << 12) + idx];
            lacc += lsb[(s << 6) + row];
        }
        yb[(size_t)(b * 1024 + t * 64 + row) * 1024 + h * 64 + col] = f2b(acc / lacc);
    }
}

extern "C" void kernel_launch(void* const* d_in, const int* in_sizes, int n_in,
                              void* d_out, int out_size, void* d_ws, size_t ws_size,
                              hipStream_t stream) {
    const float* x      = (const float*)d_in[0];
    const float* w_attn = (const float*)d_in[1];
    const float* w_proj = (const float*)d_in[2];
    const float* embk   = (const float*)d_in[3];
    const float* embv   = (const float*)d_in[4];
    float* out = (float*)d_out;

    u16* wsb   = (u16*)d_ws;
    u16* qkvb  = wsb;                  // 4096*3072 (only Q cols live now)
    u16* xb    = qkvb + 12582912;      // 4096*1024            = 4194304
    u16* ymidb = xb;                   // aliases xb (xb dead after gemm1)
    u16* waT   = xb + 4194304;         // 3072*1024            = 3145728
    u16* wpT   = waT + 3145728;        // 1024*1024            = 1048576
    u16* Vt    = wpT + 1048576;        // (slot unused; layout kept stable)
    u16* Kp    = Vt + 4194304;         // 64*64*2*512          = 4194304
    u16* Vp    = Kp + 4194304;         // 64*4*32*512          = 4194304
    u16* EKP   = Vp + 4194304;         // 72*2*512             = 73728
    u16* EVP   = EKP + 73728;          // 4*36*512             = 73728
    float* po  = (float*)(EVP + 73728);// 64*19*4096 f32       = 4980736 f32
    float* lsp = po + 4980736;         // 64*19*64 f32         = 77824 f32

    prep_all<<<dim3(5192), 256, 0, stream>>>(x, embk, embv, w_attn, w_proj,
                                             xb, EKP, EVP, waT, wpT);
    gemm_mfma<u16><<<dim3(768), 256, 0, stream>>>(xb, waT, qkvb, Kp, Vp,
                                                  4096, 3072, 1024);
    attn_mfma<<<dim3(1152), 256, 0, stream>>>(qkvb, Kp, Vp, EKP, EVP, ymidb, po, lsp);
    attn_reduce<<<dim3(9, 64), 256, 0, stream>>>(po, lsp, ymidb);
    gemm_mfma64<float><<<dim3(8, 64), 256, 0, stream>>>(ymidb, wpT, out, 4096, 1024, 1024);
}

// Round 20
// 228.357 us; speedup vs baseline: 1.0360x; 1.0093x over previous
//
#include <hip/hip_runtime.h>
#include <math.h>

typedef unsigned short u16;
typedef short bf8 __attribute__((ext_vector_type(8)));      // 8 bf16 (raw bits)
typedef float f32x4 __attribute__((ext_vector_type(4)));

__device__ __forceinline__ u16 f2b(float f) {
    union { float f; unsigned u; } x; x.f = f;
    return (u16)((x.u + 0x7FFFu + ((x.u >> 16) & 1u)) >> 16);   // RTNE
}
__device__ __forceinline__ float b2f(u16 b) {
    union { unsigned u; float f; } x; x.u = ((unsigned)b) << 16;
    return x.f;
}

__device__ __forceinline__ void async16(const void* g, void* l) {
    __builtin_amdgcn_global_load_lds(
        (const __attribute__((address_space(1))) unsigned int*)g,
        (__attribute__((address_space(3))) unsigned int*)l, 16, 0, 0);
}

__device__ __forceinline__ void cstore(float* p, float v) { *p = v; }
__device__ __forceinline__ void cstore(u16* p, float v) { *p = f2b(v); }

// ---------------- bf16 MFMA GEMM (m97 structure): C[M,N] = A[M,K] @ Bt[N,K]^T ------
// BK=32 (R12: BK=64 regressed). R14 K-FUSION + R15 V-FUSION (bit-identical,
// pack kernels deleted). R19 XCD SWIZZLE (WIN, -2.5us): 1D grid 768; each XCD
// owns a 12(bx) x 8(by) rectangle — per-XCD working set 5MB ~ L2.
template<typename OutT>
__global__ __launch_bounds__(256) void gemm_mfma(const u16* __restrict__ A,
                                                 const u16* __restrict__ Bt,
                                                 OutT* __restrict__ C,
                                                 u16* __restrict__ KP,
                                                 u16* __restrict__ VP,
                                                 int M, int N, int K) {
    __shared__ __align__(16) u16 sh[128 * 128];    // K-loop: As=[0,4096) Bs=[4096,8192); epilogue: ts[128][128]
    u16* As = sh;
    u16* Bs = sh + 128 * 32;
    const int tid = threadIdx.x;
    const int w = tid >> 6, L = tid & 63;
    const int l15 = L & 15, quad = L >> 4;
    const int wm = (w >> 1) * 64, wn = (w & 1) * 64;
    const int bid = blockIdx.x;                    // [0, 768)
    const int xcd = bid & 7, sblk = bid >> 3;
    const int bx = (xcd & 1) * 12 + (sblk % 12);
    const int by = (xcd >> 1) * 8 + (sblk / 12);
    const int row0 = by * 128, col0 = bx * 128;
    const int laneRow = L >> 2, laneCol8 = (L & 3) * 8;

    f32x4 acc[4][4] = {};

    for (int k0 = 0; k0 < K; k0 += 32) {
        #pragma unroll
        for (int i = 0; i < 2; ++i) {
            const int seg = w * 2 + i;
            const int r = seg * 16 + laneRow;
            async16(&A[(size_t)(row0 + r) * K + k0 + laneCol8], &As[seg * 512 + L * 8]);
        }
        #pragma unroll
        for (int i = 0; i < 2; ++i) {
            const int seg = w * 2 + i;
            const int r = seg * 16 + laneRow;
            async16(&Bt[(size_t)(col0 + r) * K + k0 + laneCol8], &Bs[seg * 512 + L * 8]);
        }
        __syncthreads();
        bf8 a[4], b[4];
        #pragma unroll
        for (int mt = 0; mt < 4; ++mt)
            a[mt] = *(const bf8*)&As[(wm + mt * 16 + l15) * 32 + quad * 8];
        #pragma unroll
        for (int nt = 0; nt < 4; ++nt)
            b[nt] = *(const bf8*)&Bs[(wn + nt * 16 + l15) * 32 + quad * 8];
        #pragma unroll
        for (int mt = 0; mt < 4; ++mt)
            #pragma unroll
            for (int nt = 0; nt < 4; ++nt)
                acc[mt][nt] = __builtin_amdgcn_mfma_f32_16x16x32_bf16(
                    a[mt], b[nt], acc[mt][nt], 0, 0, 0);
        __syncthreads();
    }
    if (VP != nullptr && col0 >= 2048) {
        // V-block: transpose through LDS, emit Vp fragments (pack_v fused here)
        u16* ts = sh;                              // [s_local][hl*64 + d], 128x128
        #pragma unroll
        for (int mt = 0; mt < 4; ++mt)
            #pragma unroll
            for (int nt = 0; nt < 4; ++nt) {
                const int cloc = wn + nt * 16 + l15;
                #pragma unroll
                for (int r = 0; r < 4; ++r) {
                    const int rloc = wm + mt * 16 + quad * 4 + r;
                    ts[rloc * 128 + cloc] = f2b(acc[mt][nt][r]);
                }
            }
        __syncthreads();
        const int b = row0 >> 10;
        const int h0 = (col0 - 2048) >> 6;
        const int c32base = (row0 >> 5) & 31;
        #pragma unroll
        for (int j = 0; j < 8; ++j) {
            const int f = j * 256 + tid;           // frag id in [0, 2048)
            const int hl = f >> 10, tn2 = (f >> 8) & 3, c32l = (f >> 6) & 3;
            const int Lf = f & 63, l15f = f & 15, quadf = (f >> 4) & 3;
            __align__(16) u16 buf[8];
            #pragma unroll
            for (int i = 0; i < 8; ++i)
                buf[i] = ts[(c32l * 32 + quadf * 8 + i) * 128 + hl * 64 + tn2 * 16 + l15f];
            const int bh = (b << 4) + h0 + hl;
            *(uint4*)(VP + ((size_t)(bh * 8192 + tn2 * 2048 + (c32base + c32l) * 64 + Lf) << 3))
                = *(uint4*)buf;
        }
    } else if (KP != nullptr && col0 >= 1024) {
        // K-block: emit fragment-linear Kp (pre-scaled by 1/8)
        #pragma unroll
        for (int mt = 0; mt < 4; ++mt)
            #pragma unroll
            for (int nt = 0; nt < 4; ++nt) {
                const int hd = col0 - 1024 + wn + nt * 16 + l15;
                const int h = hd >> 6, d = hd & 63;
                const int doff = ((d >> 5) << 6) + (((d >> 3) & 3) << 4);
                #pragma unroll
                for (int r = 0; r < 4; ++r) {
                    const int row = row0 + wm + mt * 16 + quad * 4 + r;
                    const int b = row >> 10, s = row & 1023;
                    const size_t idx =
                        ((size_t)((((b << 4) + h) << 13) + ((s >> 4) << 7) + doff + (s & 15)) << 3)
                        + (d & 7);
                    KP[idx] = f2b(acc[mt][nt][r] * 0.125f);
                }
            }
    } else {
        #pragma unroll
        for (int mt = 0; mt < 4; ++mt)
            #pragma unroll
            for (int nt = 0; nt < 4; ++nt) {
                const int col = col0 + wn + nt * 16 + l15;
                #pragma unroll
                for (int r = 0; r < 4; ++r) {
                    const int row = row0 + wm + mt * 16 + quad * 4 + r;
                    cstore(&C[(size_t)row * N + col], acc[mt][nt][r]);
                }
            }
    }
}

// ---------------- 64x128-tile variant (gemm2): 2 blocks/CU — the optimum ----------
// Bracketed: 128x128 @1 blk/CU slow, 64x128 @2 blk/CU best (R7/R15),
// 64x64 @4 blk/CU worse (R16). BK=32 (R12).
// R20 XCD SWIZZLE (T1, completes the set): 1D grid 512; 2x4 XCD rectangles:
//   xcd = bid&7, s = bid>>3, bx = (xcd&1)*4 + s%4, by = (xcd>>1)*16 + s/4.
// Bijective (8 = 2x4 bx, 64 = 4x16 by). Per-XCD: 4 B-panels (1MB) + 16
// A-panels (2MB) = 3MB <= L2; B re-reads x16, A x4 become XCD-local.
template<typename OutT>
__global__ __launch_bounds__(256) void gemm_mfma64(const u16* __restrict__ A,
                                                   const u16* __restrict__ Bt,
                                                   OutT* __restrict__ C,
                                                   int M, int N, int K) {
    __shared__ __align__(16) u16 As[64 * 32];
    __shared__ __align__(16) u16 Bs[128 * 32];
    const int tid = threadIdx.x;
    const int w = tid >> 6, L = tid & 63;
    const int l15 = L & 15, quad = L >> 4;
    const int wm = (w >> 1) * 32, wn = (w & 1) * 64;
    const int bid = blockIdx.x;                    // [0, 512)
    const int xcd = bid & 7, sblk = bid >> 3;
    const int bx = (xcd & 1) * 4 + (sblk & 3);
    const int by = (xcd >> 1) * 16 + (sblk >> 2);
    const int row0 = by * 64, col0 = bx * 128;
    const int laneRow = L >> 2, laneCol8 = (L & 3) * 8;

    f32x4 acc[2][4] = {};

    for (int k0 = 0; k0 < K; k0 += 32) {
        {   // A: 64x32 = 256 chunks, one per thread (seg = w)
            const int r = w * 16 + laneRow;
            async16(&A[(size_t)(row0 + r) * K + k0 + laneCol8], &As[w * 512 + L * 8]);
        }
        #pragma unroll
        for (int i = 0; i < 2; ++i) {   // B: 128x32 = 512 chunks, two per thread
            const int seg = w * 2 + i;
            const int r = seg * 16 + laneRow;
            async16(&Bt[(size_t)(col0 + r) * K + k0 + laneCol8], &Bs[seg * 512 + L * 8]);
        }
        __syncthreads();
        bf8 a[2], b[4];
        #pragma unroll
        for (int mt = 0; mt < 2; ++mt)
            a[mt] = *(const bf8*)&As[(wm + mt * 16 + l15) * 32 + quad * 8];
        #pragma unroll
        for (int nt = 0; nt < 4; ++nt)
            b[nt] = *(const bf8*)&Bs[(wn + nt * 16 + l15) * 32 + quad * 8];
        #pragma unroll
        for (int mt = 0; mt < 2; ++mt)
            #pragma unroll
            for (int nt = 0; nt < 4; ++nt)
                acc[mt][nt] = __builtin_amdgcn_mfma_f32_16x16x32_bf16(
                    a[mt], b[nt], acc[mt][nt], 0, 0, 0);
        __syncthreads();
    }
    #pragma unroll
    for (int mt = 0; mt < 2; ++mt)
        #pragma unroll
        for (int nt = 0; nt < 4; ++nt) {
            const int col = col0 + wn + nt * 16 + l15;
            #pragma unroll
            for (int r = 0; r < 4; ++r) {
                const int row = row0 + wm + mt * 16 + quad * 4 + r;
                cstore(&C[(size_t)row * N + col], acc[mt][nt][r]);
            }
        }
}

// ---------------- merged prep: x->bf16, EKP/EVP fragment tables, weight transposes --
__global__ __launch_bounds__(256) void prep_all(const float* __restrict__ x,
                                                const float* __restrict__ embk,
                                                const float* __restrict__ embv,
                                                const float* __restrict__ w_attn,
                                                const float* __restrict__ w_proj,
                                                u16* __restrict__ xb,
                                                u16* __restrict__ EKP,
                                                u16* __restrict__ EVP,
                                                u16* __restrict__ waT,
                                                u16* __restrict__ wpT) {
    __shared__ u16 ts[64][65];
    const int bx = blockIdx.x;
    const int tid = threadIdx.x;
    if (bx < 4096) {
        int idx = bx * 256 + tid;
        const float4 v = ((const float4*)x)[idx];
        ((ushort4*)xb)[idx] = make_ushort4(f2b(v.x), f2b(v.y), f2b(v.z), f2b(v.w));
    } else if (bx < 4132) {
        int t = (bx - 4096) * 256 + tid;           // [0, 9216)
        int L = t & 63, kc = (t >> 6) & 1, k16 = t >> 7;
        int l15 = L & 15, quad = L >> 4;
        int row = 1 + k16 * 16 + l15;
        int d = row - 128;
        int cl = d < 0 ? 0 : (d > 1023 ? 1023 : d);
        const float* p = embk + cl * 64 + kc * 32 + quad * 8;
        #pragma unroll
        for (int i = 0; i < 8; ++i) EKP[t * 8 + i] = f2b(p[i]);
    } else if (bx < 4168) {
        int t = (bx - 4132) * 256 + tid;           // [0, 9216)
        int L = t & 63, rest = t >> 6;             // rest = tn*36 + c32
        int c32 = rest % 36, tn = rest / 36;
        int l15 = L & 15, quad = L >> 4;
        #pragma unroll
        for (int i = 0; i < 8; ++i) {
            int c = c32 * 32 + quad * 8 + i;
            int d = c - 127;
            int cl = d < 0 ? 0 : (d > 1023 ? 1023 : d);
            EVP[t * 8 + i] = f2b(embv[cl * 64 + tn * 16 + l15]);
        }
    } else {
        const float* W; u16* WT; int Cc, t;
        if (bx < 4168 + 768) { t = bx - 4168; W = w_attn; WT = waT; Cc = 3072; }
        else                 { t = bx - 4936; W = w_proj; WT = wpT; Cc = 1024; }
        const int nx = Cc >> 6;
        const int c0 = (t % nx) * 64, r0 = (t / nx) * 64;
        for (int i = tid; i < 4096; i += 256) {
            int r = i >> 6, c = i & 63;
            ts[r][c] = f2b(W[(size_t)(r0 + r) * Cc + c0 + c]);
        }
        __syncthreads();
        for (int i = tid; i < 4096; i += 256) {
            int c = i >> 6, r = i & 63;
            WT[(size_t)(c0 + c) * 1024 + r0 + r] = ts[r][c];
        }
    }
}

// cumulative chunk counts: tile t owns units [S(t), S(t)+t/2+1); S(16)=72 total.
__device__ const int d_S[17] = {0,1,2,4,6,9,12,16,20,25,30,36,42,49,56,64,72};
// partial-slot base per split tile (tiles 4, 8..15), compact: 19 slots per bh.
// tile:       0  1  2  3  4  5  6  7  8  9 10 11 12 13 14 15
__device__ const int d_SB[16] = {0,0,0,0, 0,0,0,0, 2, 4, 6, 8,10,13,15,17};

// ---------------- MFMA fused attention with RPE: split-barrier staged pipeline -----
// R18 XCD SWIZZLE (WIN: FETCH 65->13.6MB): 1D grid 1152;
//   xcd = bid&7, slot = bid>>3, bh = (slot/18)*8 + xcd, blk = slot%18.
// R8 schedule (PROVEN): bar1 -> K DMA -> S2 covers K -> V DMA LAST ->
// vmcnt(4) (V in flight) -> s_barrier -> S1 -> softmax+scatter (covers V) ->
// bar3 -> PV + P'EV. setprio(1) on MFMA clusters.
// R9/R10: deeper pipelining costs registers/occupancy — keep body lean.
// Plain __launch_bounds__(256): hints spill (R3/R4). Keep K/V staging (R1/R5).
__global__ __launch_bounds__(256) void attn_mfma(const u16* __restrict__ qkvb,
                                                 const u16* __restrict__ Kp,
                                                 const u16* __restrict__ Vp,
                                                 const u16* __restrict__ EKP,
                                                 const u16* __restrict__ EVP,
                                                 u16* __restrict__ yb,
                                                 float* __restrict__ po,
                                                 float* __restrict__ lsp) {
    __shared__ __align__(16) u16 slab_[4][2560];   // 20480 B, per-wave overlay
    __shared__ __align__(16) u16 KVs[16384];       // 32768 B: K [0..8192), V [8192..)

    const int tid = threadIdx.x;
    const int w = tid >> 6, L = tid & 63;
    const int l15 = L & 15, quad = L >> 4;
    const int bid = blockIdx.x;                    // [0, 1152)
    const int xcd = bid & 7, slot = bid >> 3;
    const int bh = (slot / 18) * 8 + xcd;
    const int blk = slot % 18;
    const int b = bh >> 4, h = bh & 15;
    u16* S2l = slab_[w];
    u16* Pl  = slab_[w];
    u16* Ppl = slab_[w];

    const bf8* EKPF = (const bf8*)EKP;
    const bf8* EVPF = (const bf8*)EVP;

    bf8 qn[2];
    f32x4 o[4];
    float lsum[4];
    int t = -1, t0 = 0;

    auto flush = [&](int tt) {
        float lr[4];
        #pragma unroll
        for (int r = 0; r < 4; ++r) {
            float s = lsum[r];
            s += __shfl_xor(s, 1); s += __shfl_xor(s, 2);
            s += __shfl_xor(s, 4); s += __shfl_xor(s, 8);
            lr[r] = s;
        }
        const bool whole = (d_S[tt] >> 2) == ((d_S[tt + 1] - 1) >> 2);
        if (whole) {           // all units of this tile in this block: finalize
            #pragma unroll
            for (int tn = 0; tn < 4; ++tn) {
                const int col = h * 64 + tn * 16 + l15;
                #pragma unroll
                for (int r = 0; r < 4; ++r) {
                    const int trow = tt * 64 + w * 16 + quad * 4 + r;
                    yb[(size_t)(b * 1024 + trow) * 1024 + col] = f2b(o[tn][r] / lr[r]);
                }
            }
        } else {               // partial: statically-indexed slot
            const int slot2 = blk - (d_S[tt] >> 2);
            const size_t sidx = (size_t)(bh * 19 + d_SB[tt] + slot2);
            float* pob = po + (sidx << 12);
            #pragma unroll
            for (int tn = 0; tn < 4; ++tn)
                #pragma unroll
                for (int r = 0; r < 4; ++r)
                    pob[(w * 16 + quad * 4 + r) * 64 + tn * 16 + l15] = o[tn][r];
            if (l15 == 0) {
                float* lsb = lsp + (sidx << 6);
                #pragma unroll
                for (int r = 0; r < 4; ++r) lsb[w * 16 + quad * 4 + r] = lr[r];
            }
        }
    };

    #pragma unroll 1
    for (int ui = 0; ui < 4; ++ui) {
        const int u = blk * 4 + ui;
        int nt = (t < 0) ? 0 : t;
        while (d_S[nt + 1] <= u) ++nt;
        if (nt != t) {
            if (t >= 0) flush(t);
            t = nt; t0 = t * 64;
            const int trow = t0 + w * 16 + l15;
            const u16* qp = qkvb + (size_t)(b * 1024 + trow) * 3072 + h * 64 + quad * 8;
            qn[0] = *(const bf8*)qp;
            qn[1] = *(const bf8*)(qp + 32);
            #pragma unroll
            for (int tn = 0; tn < 4; ++tn)
                #pragma unroll
                for (int j = 0; j < 4; ++j) o[tn][j] = 0.f;
            #pragma unroll
            for (int r = 0; r < 4; ++r) lsum[r] = 0.f;
        }
        const int c = u - d_S[t];
        const int s0 = c << 7;
        const int diff = t0 - s0;                 // >= 0, multiple of 64

        __syncthreads();    // bar1: prior unit's LDS reads retired (drain ~free)

        // ---- issue K DMA only (16 KB contiguous) ----
        {
            const size_t kbase = ((size_t)(bh * 64 + (s0 >> 4)) << 1) * 512;
            #pragma unroll
            for (int i = 0; i < 4; ++i)
                async16(Kp + kbase + (i * 256 + tid) * 8, &KVs[(i * 256 + tid) * 8]);
        }

        // ---- S2 = Q @ EK^T (global EKP stream; covers K DMA latency) ----
        f32x4 s2[9] = {};
        {
            const int kb = (diff >> 4) + w;       // k16 base
            #pragma unroll
            for (int j = 0; j < 9; ++j) {
                #pragma unroll
                for (int kc = 0; kc < 2; ++kc)
                    s2[j] = __builtin_amdgcn_mfma_f32_16x16x32_bf16(
                        qn[kc], EKPF[(((kb + j) << 1) + kc) * 64 + L], s2[j], 0, 0, 0);
            }
        }
        #pragma unroll
        for (int j = 0; j < 9; ++j)
            #pragma unroll
            for (int r = 0; r < 4; ++r)
                S2l[(quad * 4 + r) * 148 + j * 16 + l15] = f2b(s2[j][r]);

        // ---- issue V DMA LAST (latency hides under S1 + softmax + scatter) ----
        __builtin_amdgcn_sched_barrier(0);   // pin V issue after all S2 loads
        {
            const int vb = bh * 128 + (s0 >> 5);
            #pragma unroll
            for (int i = 0; i < 4; ++i)
                async16(Vp + ((size_t)(vb + i * 32) * 512 + tid * 8),
                        &KVs[8192 + i * 2048 + tid * 8]);
        }

        // ---- wait K only (4 oldest VMEM; V stays in flight), rendezvous ----
        asm volatile("s_waitcnt vmcnt(4)" ::: "memory");
        __builtin_amdgcn_s_barrier();
        __builtin_amdgcn_sched_barrier(0);

        // ---- S1 = Q @ (K/8)^T from LDS ----
        f32x4 s1[8];
        __builtin_amdgcn_s_setprio(1);
        #pragma unroll
        for (int tn = 0; tn < 8; ++tn) {
            f32x4 z = {};
            #pragma unroll
            for (int kc = 0; kc < 2; ++kc) {
                const bf8 kf = *(const bf8*)&KVs[((tn << 1) + kc) * 512 + L * 8];
                z = __builtin_amdgcn_mfma_f32_16x16x32_bf16(qn[kc], kf, z, 0, 0, 0);
            }
            s1[tn] = z;
        }
        __builtin_amdgcn_s_setprio(0);

        // ---- logits + mask + p = exp(logit - 4); per-lane partial sums ----
        #pragma unroll
        for (int tn = 0; tn < 8; ++tn) {
            const int cl = tn * 16 + l15;
            #pragma unroll
            for (int r = 0; r < 4; ++r) {
                const int row = quad * 4 + r;
                float v = s1[tn][r] + b2f(S2l[row * 148 + (row - cl + 127)]);
                if (cl > diff + w * 16 + row) v = -1e30f;
                float p = __expf(v - 4.0f);       // masked -> 0
                s1[tn][r] = p;
                lsum[r] += p;
            }
        }

        // ---- scatter P in MFMA A-layout (clobbers dead S2l region) ----
        #pragma unroll
        for (int tn = 0; tn < 8; ++tn) {
            const int cl = tn * 16 + l15;
            #pragma unroll
            for (int r = 0; r < 4; ++r) {
                const int row = quad * 4 + r;
                Pl[((cl >> 5) << 9) + (((cl >> 3) & 3) << 7) + (row << 3) + (cl & 7)]
                    = f2b(s1[tn][r]);
            }
        }
        // ---- read P fragments (in-order DS: reads precede overlay writes) ----
        bf8 pa[4];
        #pragma unroll
        for (int kc = 0; kc < 4; ++kc) pa[kc] = ((const bf8*)Pl)[kc * 64 + L];

        // ---- rebuild overlay as sheared P' (zero pads, then scatter) ----
        #pragma unroll
        for (int i = 0; i < 5; ++i)
            ((uint4*)Ppl)[i * 64 + L] = make_uint4(0, 0, 0, 0);
        #pragma unroll
        for (int tn = 0; tn < 8; ++tn) {
            const int cl = tn * 16 + l15;
            #pragma unroll
            for (int r = 0; r < 4; ++r) {
                const int row = quad * 4 + r;
                const int dc = (w & 1) * 16 + row - cl + 127;   // [0,158]
                Ppl[((dc >> 5) << 9) + (((dc >> 3) & 3) << 7) + (row << 3) + (dc & 7)]
                    = f2b(s1[tn][r]);
            }
        }

        __syncthreads();    // bar3: V visible to all waves (drain ~free, V landed)
        __builtin_amdgcn_sched_barrier(0);

        // ---- O += P @ V (V frags from LDS) ----
        __builtin_amdgcn_s_setprio(1);
        {
            #pragma unroll
            for (int tn = 0; tn < 4; ++tn) {
                #pragma unroll
                for (int kc = 0; kc < 4; ++kc) {
                    const bf8 vf = *(const bf8*)&KVs[8192 + (tn * 4 + kc) * 512 + L * 8];
                    o[tn] = __builtin_amdgcn_mfma_f32_16x16x32_bf16(
                        pa[kc], vf, o[tn], 0, 0, 0);
                }
            }
        }
        // ---- O += P' @ EV (global EVP stream) ----
        {
            bf8 pb[5];
            #pragma unroll
            for (int kc = 0; kc < 5; ++kc) pb[kc] = ((const bf8*)Ppl)[kc * 64 + L];
            const int eb = (diff >> 5) + (w >> 1);
            #pragma unroll
            for (int tn = 0; tn < 4; ++tn) {
                #pragma unroll
                for (int kc = 0; kc < 5; ++kc)
                    o[tn] = __builtin_amdgcn_mfma_f32_16x16x32_bf16(
                        pb[kc], EVPF[(tn * 36 + eb + kc) * 64 + L], o[tn], 0, 0, 0);
            }
        }
        __builtin_amdgcn_s_setprio(0);
    }
    flush(t);
}

// ---------------- combine partial (o, lsum) slots for split tiles, normalize -------
__global__ __launch_bounds__(256) void attn_reduce(const float* __restrict__ po,
                                                   const float* __restrict__ lsp,
                                                   u16* __restrict__ yb) {
    const int gi = blockIdx.x;                    // 0 -> tile 4, i -> tile i+7
    const int t = (gi == 0) ? 4 : (gi + 7);
    const int bh = blockIdx.y, b = bh >> 4, h = bh & 15;
    const int ns = (t == 12) ? 3 : 2;
    const size_t base = (size_t)(bh * 19 + d_SB[t]);
    const float* pob = po + (base << 12);
    const float* lsb = lsp + (base << 6);
    #pragma unroll 1
    for (int i = 0; i < 16; ++i) {
        const int idx = i * 256 + threadIdx.x;
        const int row = idx >> 6, col = idx & 63;
        float acc = 0.f, lacc = 0.f;
        for (int s = 0; s < ns; ++s) {
            acc  += pob[(s << 12) + idx];
            lacc += lsb[(s << 6) + row];
        }
        yb[(size_t)(b * 1024 + t * 64 + row) * 1024 + h * 64 + col] = f2b(acc / lacc);
    }
}

extern "C" void kernel_launch(void* const* d_in, const int* in_sizes, int n_in,
                              void* d_out, int out_size, void* d_ws, size_t ws_size,
                              hipStream_t stream) {
    const float* x      = (const float*)d_in[0];
    const float* w_attn = (const float*)d_in[1];
    const float* w_proj = (const float*)d_in[2];
    const float* embk   = (const float*)d_in[3];
    const float* embv   = (const float*)d_in[4];
    float* out = (float*)d_out;

    u16* wsb   = (u16*)d_ws;
    u16* qkvb  = wsb;                  // 4096*3072 (only Q cols live now)
    u16* xb    = qkvb + 12582912;      // 4096*1024            = 4194304
    u16* ymidb = xb;                   // aliases xb (xb dead after gemm1)
    u16* waT   = xb + 4194304;         // 3072*1024            = 3145728
    u16* wpT   = waT + 3145728;        // 1024*1024            = 1048576
    u16* Vt    = wpT + 1048576;        // (slot unused; layout kept stable)
    u16* Kp    = Vt + 4194304;         // 64*64*2*512          = 4194304
    u16* Vp    = Kp + 4194304;         // 64*4*32*512          = 4194304
    u16* EKP   = Vp + 4194304;         // 72*2*512             = 73728
    u16* EVP   = EKP + 73728;          // 4*36*512             = 73728
    float* po  = (float*)(EVP + 73728);// 64*19*4096 f32       = 4980736 f32
    float* lsp = po + 4980736;         // 64*19*64 f32         = 77824 f32

    prep_all<<<dim3(5192), 256, 0, stream>>>(x, embk, embv, w_attn, w_proj,
                                             xb, EKP, EVP, waT, wpT);
    gemm_mfma<u16><<<dim3(768), 256, 0, stream>>>(xb, waT, qkvb, Kp, Vp,
                                                  4096, 3072, 1024);
    attn_mfma<<<dim3(1152), 256, 0, stream>>>(qkvb, Kp, Vp, EKP, EVP, ymidb, po, lsp);
    attn_reduce<<<dim3(9, 64), 256, 0, stream>>>(po, lsp, ymidb);
    gemm_mfma64<float><<<dim3(512), 256, 0, stream>>>(ymidb, wpT, out, 4096, 1024, 1024);
}